// Round 9
// baseline (469.884 us; speedup 1.0000x reference)
//
#include <hip/hip_runtime.h>
#include <math.h>

#define CHN 96
#define HW 16384
#define NWIN 31
#define SCALE_F 0.20412414523193154f
#define SCALE_L2 0.294488893f   // SCALE_F * log2(e): exp(s*SCALE) == exp2(s*SCALE_L2)

typedef __attribute__((ext_vector_type(8))) __bf16 bf16x8;
typedef __attribute__((ext_vector_type(4))) float f32x4;
typedef __attribute__((ext_vector_type(8))) unsigned short u16x8;

__device__ __forceinline__ int rfl(int v) { return __builtin_amdgcn_readfirstlane(v); }

__device__ __forceinline__ unsigned short f2bf(float f) {
  union { float f; unsigned u; } v; v.f = f;
  unsigned r = v.u + 0x7fffu + ((v.u >> 16) & 1u);
  return (unsigned short)(r >> 16);
}
__device__ __forceinline__ float bf2f(unsigned short h) {
  union { unsigned u; float f; } v; v.u = ((unsigned)h) << 16;
  return v.f;
}
__device__ __forceinline__ float fexp2(float x) {
#if __has_builtin(__builtin_amdgcn_exp2f)
  return __builtin_amdgcn_exp2f(x);
#else
  return __expf(x * 0.6931471806f);
#endif
}
__device__ __forceinline__ float ldv(const float* p, size_t i) { return p[i]; }
__device__ __forceinline__ float ldv(const unsigned short* p, size_t i) { return bf2f(p[i]); }
__device__ __forceinline__ bf16x8 ld8(const unsigned short* p) {
  return *(const bf16x8*)__builtin_assume_aligned(p, 16);
}
__device__ __forceinline__ u16x8 ld8u(const unsigned short* p) {
  return *(const u16x8*)__builtin_assume_aligned(p, 16);
}
__device__ __forceinline__ bf16x8 zf8() {
  union { unsigned long long u[2]; bf16x8 v; } z;
  z.u[0] = 0ull; z.u[1] = 0ull;
  return z.v;
}
__device__ __forceinline__ bf16x8 onesf8() {
  union { unsigned short s[8]; bf16x8 v; } o;
#pragma unroll
  for (int i = 0; i < 8; ++i) o.s[i] = 0x3F80;  // bf16 1.0
  return o.v;
}
// V B-frag direct from channel-major global: 8 consecutive gx of one row, as two
// 8B-aligned ushort4 chunks; (gx0+4)&127 handles the shift=4,wx=30 wrap (matches
// the old staging's per-chunk &127 exactly -> bit-identical values).
__device__ __forceinline__ bf16x8 ldv8row(const unsigned short* rowp, int gx0) {
  union { ushort4 q[2]; bf16x8 v; } u;
  u.q[0] = *(const ushort4*)__builtin_assume_aligned(rowp + gx0, 8);
  u.q[1] = *(const ushort4*)__builtin_assume_aligned(rowp + ((gx0 + 4) & 127), 8);
  return u.v;
}
// vector load helpers: 8 / 4 floats from fp32 or bf16 source
__device__ __forceinline__ void ld8f(const float* p, float* o) {
  float4 a = *(const float4*)__builtin_assume_aligned(p, 16);
  float4 b = *(const float4*)__builtin_assume_aligned(p + 4, 16);
  o[0] = a.x; o[1] = a.y; o[2] = a.z; o[3] = a.w;
  o[4] = b.x; o[5] = b.y; o[6] = b.z; o[7] = b.w;
}
__device__ __forceinline__ void ld8f(const unsigned short* p, float* o) {
  u16x8 v = ld8u(p);
#pragma unroll
  for (int u = 0; u < 8; ++u) o[u] = bf2f(v[u]);
}
__device__ __forceinline__ void ld4f(const float* p, float* o) {
  float4 a = *(const float4*)__builtin_assume_aligned(p, 16);
  o[0] = a.x; o[1] = a.y; o[2] = a.z; o[3] = a.w;
}
__device__ __forceinline__ void ld4f(const unsigned short* p, float* o) {
  ushort4 v = *(const ushort4*)__builtin_assume_aligned(p, 8);
  o[0] = bf2f(v.x); o[1] = bf2f(v.y); o[2] = bf2f(v.z); o[3] = bf2f(v.w);
}

// GELU via x*sigmoid(1.702x); |err vs exact| <= ~0.02 (within absmax budget)
__device__ __forceinline__ float gelu_sig(float x) {
  return x * __builtin_amdgcn_rcpf(1.f + __expf(-1.702f * x));
}

// ---------------- LN stats (pass 0 only), 4 px/thread vectorized, grid 64 ----------------
template <typename T>
__global__ __launch_bounds__(256) void ln2_k(const T* __restrict__ xl, const T* __restrict__ xh,
                                             float* __restrict__ mu_l, float* __restrict__ rs_l,
                                             float* __restrict__ mu_h, float* __restrict__ rs_h) {
  int which = blockIdx.x >> 5;           // 32 blocks per tensor
  int idx = (blockIdx.x & 31) * 256 + threadIdx.x;   // 0..8191
  int pix0 = idx * 4;                    // 0..32764
  const T* xt = which ? xh : xl;
  float* mu = which ? mu_h : mu_l;
  float* rstd = which ? rs_h : rs_l;
  int b = pix0 >> 14, p = pix0 & 16383;
  const T* xp = xt + (size_t)b * CHN * HW + p;
  float s[4] = {0.f, 0.f, 0.f, 0.f}, s2[4] = {0.f, 0.f, 0.f, 0.f};
#pragma unroll 8
  for (int c = 0; c < CHN; ++c) {
    float v4[4];
    ld4f(xp + (size_t)c * HW, v4);
#pragma unroll
    for (int j = 0; j < 4; ++j) {
      s[j] += v4[j];
      s2[j] = fmaf(v4[j], v4[j], s2[j]);
    }
  }
  float4 mo, ro;
  float m0 = s[0] * (1.f / 96.f), m1 = s[1] * (1.f / 96.f);
  float m2 = s[2] * (1.f / 96.f), m3 = s[3] * (1.f / 96.f);
  mo.x = m0; mo.y = m1; mo.z = m2; mo.w = m3;
  ro.x = rsqrtf(fmaf(-m0, m0, s2[0] * (1.f / 96.f)) + 1e-5f);
  ro.y = rsqrtf(fmaf(-m1, m1, s2[1] * (1.f / 96.f)) + 1e-5f);
  ro.z = rsqrtf(fmaf(-m2, m2, s2[2] * (1.f / 96.f)) + 1e-5f);
  ro.w = rsqrtf(fmaf(-m3, m3, s2[3] * (1.f / 96.f)) + 1e-5f);
  *(float4*)&mu[pix0] = mo;
  *(float4*)&rstd[pix0] = ro;
}

// ---------------- SE pool (4 px/iter vectorized) ----------------
template <typename T>
__global__ __launch_bounds__(256) void pool_k(const T* __restrict__ x,
                                              const float* __restrict__ mu,
                                              const float* __restrict__ rstd,
                                              const float* __restrict__ g,
                                              const float* __restrict__ bt,
                                              float* __restrict__ pool) {
  int blk = blockIdx.x;
  int b = blk / CHN, c = blk % CHN;
  const T* xp = x + (size_t)(b * CHN + c) * HW;
  const float* mup = mu + b * HW;
  const float* rp = rstd + b * HW;
  int t = threadIdx.x;
  float s = 0.f;
  for (int p0 = t * 4; p0 < HW; p0 += 1024) {
    float v4[4];
    ld4f(xp + p0, v4);
    float4 m4 = *(const float4*)&mup[p0];
    float4 r4 = *(const float4*)&rp[p0];
    s += (v4[0] - m4.x) * r4.x + (v4[1] - m4.y) * r4.y +
         (v4[2] - m4.z) * r4.z + (v4[3] - m4.w) * r4.w;
  }
  __shared__ float red[256];
  red[t] = s;
  __syncthreads();
  for (int k = 128; k > 0; k >>= 1) {
    if (t < k) red[t] += red[t + k];
    __syncthreads();
  }
  if (t == 0) pool[blk] = g[c] * (red[0] * (1.f / 16384.f)) + bt[c];
}

// ---------------- SE gate ----------------
__global__ __launch_bounds__(256) void se_k(const float* __restrict__ pool,
                                            const float* __restrict__ w1,
                                            const float* __restrict__ w2,
                                            float* __restrict__ s_se) {
  int t = threadIdx.x;
  if (t >= 2 * CHN) return;
  int b = t / CHN, c = t % CHN;
  int i = c >> 5, cl = c & 31;
  const float* pg = pool + b * CHN + i * 32;
  const float* w1p = w1 + i * 64;
  float z0 = 0.f, z1 = 0.f;
#pragma unroll 8
  for (int k = 0; k < 32; ++k) {
    float p = pg[k];
    z0 = fmaf(p, w1p[k], z0);
    z1 = fmaf(p, w1p[32 + k], z1);
  }
  z0 = fmaxf(z0, 0.f);
  z1 = fmaxf(z1, 0.f);
  float a = z0 * w2[i * 64 + cl * 2] + z1 * w2[i * 64 + cl * 2 + 1];
  s_se[t] = 1.f / (1.f + __expf(-a));
}

// ---------------- weight convert fp32 -> bf16 ----------------
__global__ __launch_bounds__(256) void cvt_k(const float* __restrict__ w1,
                                             const float* __restrict__ w2,
                                             const float* __restrict__ p0,
                                             const float* __restrict__ p1,
                                             const float* __restrict__ p2,
                                             const float* __restrict__ p3,
                                             const float* __restrict__ p4,
                                             const float* __restrict__ p5,
                                             const float* __restrict__ q0,
                                             const float* __restrict__ q1,
                                             unsigned short* __restrict__ w1b,
                                             unsigned short* __restrict__ w2b,
                                             unsigned short* __restrict__ wqb,
                                             unsigned short* __restrict__ wpb) {
  int i = blockIdx.x * 256 + threadIdx.x;
  if (i < 36864) {
    w1b[i] = f2bf(w1[i]);
    w2b[i] = f2bf(w2[i]);
  }
  if (i < 55296) {
    int tt = i / 9216, rem = i - tt * 9216;
    const float* ps[6] = {p0, p1, p2, p3, p4, p5};
    wqb[i] = f2bf(ps[tt][rem]);
  }
  if (i < 18432) {
    wpb[i] = f2bf(i < 9216 ? q0[i] : q1[i - 9216]);
  }
}

// ---------------- MFMA full-image QKV projection ----------------
// qkv slots [t][b]; Q/K (t=0,1,3,4) pixel-major [pix][96]; V (t=2,5) channel-major [c][HW].
// Staging: thread owns (channel, fixed 8-px group) -> 8-px vector loads, stats hoisted.
// LDS staging uses group-rotation swizzle: col' = (c + 8*(row>>3)) mod 96 so the
// pixel-major scatter writes spread over all 8 16B-slots mod 128 (was 16-way conflict).
template <typename T>
__global__ __launch_bounds__(256, 3) void proj_k(
    const T* __restrict__ lowp, const T* __restrict__ highp,
    const float* __restrict__ mu_l, const float* __restrict__ rs_l,
    const float* __restrict__ mu_h, const float* __restrict__ rs_h,
    const float* __restrict__ g, const float* __restrict__ bt,
    const float* __restrict__ s_se,
    const unsigned short* __restrict__ wqb,
    unsigned short* __restrict__ qkv) {
  __shared__ __align__(16) unsigned short sh[13312];  // Xl[64*104] | Xh[64*104]; later tb[4][32*104]
  unsigned short* Xl = sh;
  unsigned short* Xh = sh + 6656;
  int t = threadIdx.x;
  int lane = t & 63;
  int w = rfl(t >> 6);
  int n16 = lane & 15, quad = lane >> 4;
  int tile = blockIdx.x;
  int Pb = tile * 64;
  int b = Pb >> 14, rr0 = Pb & 16383;

  // ---- stage: thread's fixed 8 pixels = rr0 + (t&7)*8 .. +7 ----
  {
    int pg = t & 7;
    float mul8[8], rsl8[8], muh8[8], rsh8[8];
    ld8f(mu_l + (size_t)b * HW + rr0 + pg * 8, mul8);
    ld8f(rs_l + (size_t)b * HW + rr0 + pg * 8, rsl8);
    ld8f(mu_h + (size_t)b * HW + rr0 + pg * 8, muh8);
    ld8f(rs_h + (size_t)b * HW + rr0 + pg * 8, rsh8);
#pragma unroll
    for (int k = 0; k < 3; ++k) {
      int c = (t + k * 256) >> 3;
      float gc = g[c], bc = bt[c], sc = s_se[b * CHN + c];
      float xl8[8], xh8[8];
      ld8f(lowp + (size_t)(b * CHN + c) * HW + rr0 + pg * 8, xl8);
      ld8f(highp + (size_t)(b * CHN + c) * HW + rr0 + pg * 8, xh8);
      int cr = c + pg * 8; if (cr >= 96) cr -= 96;   // rotated col (row>>3 == pg)
#pragma unroll
      for (int u = 0; u < 8; ++u) {
        int px = pg * 8 + u;
        Xl[px * 104 + cr] = f2bf((xl8[u] - mul8[u]) * rsl8[u] * gc + bc);
        Xh[px * 104 + cr] = f2bf(((xh8[u] - muh8[u]) * rsh8[u] * gc + bc) * sc);
      }
    }
  }
  __syncthreads();

  // register-cache A-frags for BOTH the main (pixel-major) tensor and the V tensor
  int tmain = (0x4310 >> (4 * w)) & 15;          // w: 0->t0, 1->t1, 2->t3, 3->t4
  const unsigned short* Xm = (w == 0 || w == 3) ? Xl : Xh;
  const unsigned short* Xv = (w < 2) ? Xh : Xl;
  bf16x8 af[12], av[12];
  int rotb = n16 >> 3;
#pragma unroll
  for (int mi = 0; mi < 4; ++mi)
#pragma unroll
    for (int k = 0; k < 3; ++k) {
      int gidx = k * 4 + quad + 2 * mi + rotb; if (gidx >= 12) gidx -= 12;
      af[mi * 3 + k] = ld8(&Xm[(mi * 16 + n16) * 104 + gidx * 8]);
      av[mi * 3 + k] = ld8(&Xv[(mi * 16 + n16) * 104 + gidx * 8]);
    }
  __syncthreads();   // X dead; tb overlays

  unsigned short* tw = sh + w * 3328;
#pragma unroll
  for (int half = 0; half < 2; ++half) {
#pragma unroll
    for (int ni = 0; ni < 6; ++ni) {
      f32x4 a0 = {0.f, 0.f, 0.f, 0.f}, a1 = {0.f, 0.f, 0.f, 0.f};
#pragma unroll
      for (int k = 0; k < 3; ++k) {
        bf16x8 bf = ld8(&wqb[((size_t)tmain * 96 + ni * 16 + n16) * 96 + k * 32 + quad * 8]);
        a0 = __builtin_amdgcn_mfma_f32_16x16x32_bf16(af[(half * 2 + 0) * 3 + k], bf, a0, 0, 0, 0);
        a1 = __builtin_amdgcn_mfma_f32_16x16x32_bf16(af[(half * 2 + 1) * 3 + k], bf, a1, 0, 0, 0);
      }
#pragma unroll
      for (int r = 0; r < 4; ++r) {
        tw[(quad * 4 + r) * 104 + ni * 16 + n16] = f2bf(a0[r]);
        tw[(16 + quad * 4 + r) * 104 + ni * 16 + n16] = f2bf(a1[r]);
      }
    }
    // wave-local readout (per-wave DS ops in-order; no barrier)
#pragma unroll
    for (int c6 = 0; c6 < 6; ++c6) {
      int chunk = lane + 64 * c6;
      int pl2 = chunk / 12, kb2 = chunk - pl2 * 12;
      u16x8 v = ld8u(&tw[pl2 * 104 + kb2 * 8]);
      size_t pix = (size_t)rr0 + half * 32 + pl2;
      *(u16x8*)&qkv[((size_t)(tmain * 2 + b) * HW + pix) * 96 + kb2 * 8] = v;
    }
  }

  // V units from register-cached av
  int tv = (w < 2) ? 2 : 5;
  int nbase = (w & 1) * 3;
#pragma unroll
  for (int jj = 0; jj < 3; ++jj) {
    int ni = nbase + jj;
    f32x4 acc[4];
#pragma unroll
    for (int mi = 0; mi < 4; ++mi) { f32x4 z = {0.f, 0.f, 0.f, 0.f}; acc[mi] = z; }
#pragma unroll
    for (int k = 0; k < 3; ++k) {
      bf16x8 bf = ld8(&wqb[((size_t)tv * 96 + ni * 16 + n16) * 96 + k * 32 + quad * 8]);
#pragma unroll
      for (int mi = 0; mi < 4; ++mi)
        acc[mi] = __builtin_amdgcn_mfma_f32_16x16x32_bf16(av[mi * 3 + k], bf, acc[mi], 0, 0, 0);
    }
    int feat = ni * 16 + n16;
    size_t rowbase = ((size_t)(tv * 2 + b) * CHN + feat) * HW + rr0;
#pragma unroll
    for (int mi = 0; mi < 4; ++mi) {
      ushort4 o4;
      o4.x = f2bf(acc[mi][0]);
      o4.y = f2bf(acc[mi][1]);
      o4.z = f2bf(acc[mi][2]);
      o4.w = f2bf(acc[mi][3]);
      *(ushort4*)&qkv[rowbase + mi * 16 + quad * 4] = o4;
    }
  }
}

// ---------------- MFMA window attention (both dirs fused in one launch) ----------------
// grid = 2 dirs x 2 batches x 961 windows = 3844 blocks. Owin slot (dir*2 + b).
// XCD swizzle: 3844 % 8 = 4 -> bijective chunked variant (q=480, r=4):
//   chunk start = x<4 ? x*481 : 1924 + (x-4)*480   (x = bid0 & 7, y = bid0 >> 3)
// [R7 ERRATA: naive remap at nwg=3844 skipped half the windows; absmax was the tell.]
// R9: V LDS staging DELETED — the PV B-frag (h*24+n16 channel, 8 consecutive window
// px of one row) is a contiguous run in channel-major global V; load it directly as
// two 8B ushort4 chunks with (gx0+4)&127 wrap (bit-identical to old staging).
// LDS is now P32 only (18432 B, Os overlays) -> 8 blocks/CU (was ~5) for the
// latency-bound regime; V-staging phase + one barrier removed; all global loads
// (Q,K,V) issued in one batch at kernel start (T14).
__global__ __launch_bounds__(256, 8) void attn_k(
    const unsigned short* __restrict__ qkv,
    unsigned short* __restrict__ Owin, int shift) {
  __shared__ __align__(16) unsigned short shb[9216];  // P32[4][64*36]; Os[64*104] overlays
  unsigned short* P32 = shb;
  unsigned short* Os = shb;

  int bid0 = blockIdx.x;
  int x8 = bid0 & 7, y8 = bid0 >> 3;
  int bid = (x8 < 4 ? x8 * 481 : 1924 + (x8 - 4) * 480) + y8;  // bijective on [0,3844)
  int dir = bid / 1922;
  int rem = bid - dir * 1922;
  int b = rem / 961;
  int win = rem - b * 961;
  int wy = win / NWIN, wx = win % NWIN;
  int t = threadIdx.x;
  int lane = t & 63;
  int h = rfl(t >> 6);
  int n16 = lane & 15, quad = lane >> 4;

  // ---- T14: issue ALL global loads (Q x4, K x4, V x4 frags) up front ----
  bf16x8 qa[4], kb4[4];
  {
    const unsigned short* qpm = qkv + (size_t)((dir * 3 + 0) * 2 + b) * CHN * HW;
    const unsigned short* kpm = qkv + (size_t)((dir * 3 + 1) * 2 + b) * CHN * HW;
    if (quad < 3) {
#pragma unroll
      for (int ni = 0; ni < 4; ++ni) {
        int n = ni * 16 + n16;
        int gy = (wy * 4 + (n >> 3) + shift) & 127;
        int gx = (wx * 4 + (n & 7) + shift) & 127;
        size_t pix = (size_t)gy * 128 + gx;
        qa[ni] = ld8(&qpm[pix * 96 + h * 24 + quad * 8]);
        kb4[ni] = ld8(&kpm[pix * 96 + h * 24 + quad * 8]);
      }
    } else {
#pragma unroll
      for (int ni = 0; ni < 4; ++ni) { qa[ni] = zf8(); kb4[ni] = zf8(); }
    }
  }

  // V frags direct from global (vb[s][0]: c = h*24+n16; vb[s][1]: c = h*24+16+n16, n16<8)
  bf16x8 vb[2][2];
  {
    const unsigned short* vbase = qkv + (size_t)((dir * 3 + 2) * 2 + b) * CHN * HW;
    int gx0 = wx * 4 + shift;            // <= 124, multiple of 4
#pragma unroll
    for (int s = 0; s < 2; ++s) {
      int gy = (wy * 4 + s * 4 + quad + shift) & 127;
      const unsigned short* row0 = vbase + (size_t)(h * 24 + n16) * HW + gy * 128;
      vb[s][0] = ldv8row(row0, gx0);
      if (n16 < 8) {
        const unsigned short* row1 = vbase + (size_t)(h * 24 + 16 + n16) * HW + gy * 128;
        vb[s][1] = ldv8row(row1, gx0);
      } else {
        vb[s][1] = zf8();
      }
    }
  }

  const int hP = h * (64 * 36);

  f32x4 sa[4][4];
#pragma unroll
  for (int ni = 0; ni < 4; ++ni)
#pragma unroll
    for (int mi = 0; mi < 4; ++mi) {
      f32x4 z = {0.f, 0.f, 0.f, 0.f};
      sa[ni][mi] = __builtin_amdgcn_mfma_f32_16x16x32_bf16(qa[ni], kb4[mi], z, 0, 0, 0);
    }

  // unnormalized exponentials (no-max softmax; scores bounded)
#pragma unroll
  for (int ni = 0; ni < 4; ++ni)
#pragma unroll
    for (int mi = 0; mi < 4; ++mi)
#pragma unroll
      for (int r = 0; r < 4; ++r)
        sa[ni][mi][r] = fexp2(sa[ni][mi][r] * SCALE_L2);

  const bf16x8 ones = onesf8();
  f32x4 oa[4][2];
  f32x4 sacc[4];
#pragma unroll
  for (int ni = 0; ni < 4; ++ni) {
    f32x4 z = {0.f, 0.f, 0.f, 0.f};
    oa[ni][0] = z; oa[ni][1] = z; sacc[ni] = z;
  }
#pragma unroll
  for (int s = 0; s < 2; ++s) {
    // P32 is per-wave scratch (hP offset): ds ops are wave-local & in-order, no barrier
#pragma unroll
    for (int ni = 0; ni < 4; ++ni)
#pragma unroll
      for (int r = 0; r < 4; ++r) {
#pragma unroll
        for (int mm = 0; mm < 2; ++mm) {
          int mi = s * 2 + mm;
          P32[hP + (ni * 16 + quad * 4 + r) * 36 + mm * 16 + n16] = f2bf(sa[ni][mi][r]);
        }
      }
    bf16x8 pa[4];
#pragma unroll
    for (int ni = 0; ni < 4; ++ni) pa[ni] = ld8(&P32[hP + (ni * 16 + n16) * 36 + quad * 8]);
#pragma unroll
    for (int ni = 0; ni < 4; ++ni) {
      oa[ni][0] = __builtin_amdgcn_mfma_f32_16x16x32_bf16(pa[ni], vb[s][0], oa[ni][0], 0, 0, 0);
      oa[ni][1] = __builtin_amdgcn_mfma_f32_16x16x32_bf16(pa[ni], vb[s][1], oa[ni][1], 0, 0, 0);
      sacc[ni] = __builtin_amdgcn_mfma_f32_16x16x32_bf16(pa[ni], ones, sacc[ni], 0, 0, 0);
    }
  }

  // normalize O by MFMA-computed row sums (same accumulator layout: row = quad*4+r)
#pragma unroll
  for (int ni = 0; ni < 4; ++ni)
#pragma unroll
    for (int r = 0; r < 4; ++r) {
      float inv = __builtin_amdgcn_rcpf(sacc[ni][r]);
      oa[ni][0][r] *= inv;
      oa[ni][1][r] *= inv;
    }
  __syncthreads();   // all waves done with their P32; Os overlays

  // stage O -> Os[px][96] (pad 104), then coalesced 16B stores
#pragma unroll
  for (int ni = 0; ni < 4; ++ni)
#pragma unroll
    for (int r = 0; r < 4; ++r) {
      int n = ni * 16 + quad * 4 + r;
      Os[n * 104 + h * 24 + n16] = f2bf(oa[ni][0][r]);
      if (n16 < 8) Os[n * 104 + h * 24 + 16 + n16] = f2bf(oa[ni][1][r]);
    }
  __syncthreads();

  {
    unsigned short* obase = Owin + (size_t)((dir * 2 + b) * 961 + win) * 64 * CHN;
#pragma unroll
    for (int k = 0; k < 3; ++k) {
      int i = t + k * 256;               // 0..767
      int px = i / 12, cb = i - px * 12;
      u16x8 v = ld8u(&Os[px * 104 + cb * 8]);
      *(u16x8*)&obase[px * CHN + cb * 8] = v;
    }
  }
}

// ---------------- MFMA combine + fused next-pass LN stats (low+high fused) ----------------
// grid 1024; XCD-chunk swizzle (1024 = 8*128, divisible -> simple form is bijective).
// sel picks (low, dir0) vs (high, dir1) stream.
template <typename T>
__global__ __launch_bounds__(256) void combine_k(
    const T* __restrict__ base_l, const T* __restrict__ base_h,
    unsigned short* __restrict__ out_l, unsigned short* __restrict__ out_h,
    const unsigned short* __restrict__ Owin,
    float* __restrict__ mu_lp, float* __restrict__ rs_lp,
    float* __restrict__ mu_hp, float* __restrict__ rs_hp,
    const float* __restrict__ g, const float* __restrict__ bt,
    const unsigned short* __restrict__ wpb2, int shift) {
  __shared__ __align__(16) unsigned short sb[96 * 72];   // at [64][104] then ot [96][72]
  __shared__ float red[2][4][64];
  unsigned short* at = sb;
  unsigned short* ot = sb;
  int t = threadIdx.x;
  int lane = t & 63;
  int w = rfl(t >> 6);
  int n16 = lane & 15, quad = lane >> 4;
  int wg = (blockIdx.x & 7) * 128 + (blockIdx.x >> 3);   // bijective XCD-chunk swizzle
  int sel = wg >> 9;
  int tile = wg & 511;                   // 0..511
  const T* base = sel ? base_h : base_l;
  unsigned short* outp = sel ? out_h : out_l;
  float* mu = sel ? mu_hp : mu_lp;
  float* rstd = sel ? rs_hp : rs_lp;
  const unsigned short* wpb = wpb2 + sel * 9216;

#pragma unroll
  for (int k = 0; k < 3; ++k) {
    int i = t + k * 256;
    int px = i / 12, cb = i - px * 12;
    int Ps = tile * 64 + px;
    int b = Ps >> 14, rem = Ps & 16383;
    int ys = rem >> 7, xs = rem & 127;
    int wyh = ys >> 2, wxh = xs >> 2;
    float acc[8];
#pragma unroll
    for (int u = 0; u < 8; ++u) acc[u] = 0.f;
    for (int dy = 0; dy < 2; ++dy) {
      int wyc = wyh - 1 + dy;
      if ((unsigned)wyc > 30u) continue;
      int py = ys - wyc * 4;
      for (int dx = 0; dx < 2; ++dx) {
        int wxc = wxh - 1 + dx;
        if ((unsigned)wxc > 30u) continue;
        int pxl = xs - wxc * 4;
        size_t o = ((size_t)((sel * 2 + b) * 961 + wyc * 31 + wxc) * 64 + py * 8 + pxl) * CHN + cb * 8;
        u16x8 v = ld8u(&Owin[o]);
#pragma unroll
        for (int u = 0; u < 8; ++u) acc[u] += bf2f(v[u]);
      }
    }
    union { u16x8 v; unsigned short s[8]; } pk;
#pragma unroll
    for (int u = 0; u < 8; ++u) pk.s[u] = f2bf(acc[u]);
    *(u16x8*)&at[px * 104 + cb * 8] = pk.v;
  }
  __syncthreads();

  bf16x8 af[3];
#pragma unroll
  for (int k = 0; k < 3; ++k)
    af[k] = ld8(&at[(w * 16 + n16) * 104 + k * 32 + quad * 8]);

  f32x4 acc6[6];
#pragma unroll
  for (int ni = 0; ni < 6; ++ni) {
    f32x4 z = {0.f, 0.f, 0.f, 0.f};
    acc6[ni] = z;
#pragma unroll
    for (int k = 0; k < 3; ++k) {
      bf16x8 bf = ld8(&wpb[(ni * 16 + n16) * 96 + k * 32 + quad * 8]);
      acc6[ni] = __builtin_amdgcn_mfma_f32_16x16x32_bf16(af[k], bf, acc6[ni], 0, 0, 0);
    }
  }
  __syncthreads();

#pragma unroll
  for (int ni = 0; ni < 6; ++ni)
#pragma unroll
    for (int r = 0; r < 4; ++r)
      ot[(ni * 16 + n16) * 72 + w * 16 + quad * 4 + r] = f2bf(acc6[ni][r]);
  __syncthreads();

  int Ps0 = tile * 64;
  int b = Ps0 >> 14, rem0 = Ps0 & 16383;
  int ys = rem0 >> 7, xs0 = rem0 & 127;
  int yt = (ys + shift) & 127;
  float icy = (ys >= 4 && ys <= 123) ? 0.5f : 1.f;
  int px = t & 63, c0w = t >> 6;
  int xs = xs0 + px;
  int xt = (xs + shift) & 127;
  float icx = (xs >= 4 && xs <= 123) ? 0.5f : 1.f;
  float invc = icy * icx;
  int pt = b * HW + yt * 128 + xt;
  float m = mu[pt], rs = rstd[pt];
  size_t pixoff = (size_t)yt * 128 + xt;
  float s = 0.f, sq = 0.f;
#pragma unroll
  for (int k = 0; k < 24; ++k) {
    int o = c0w + 4 * k;
    size_t gidx = ((size_t)b * CHN + o) * HW + pixoff;
    float bv = ldv(base, gidx);
    float lnv = (bv - m) * rs * g[o] + bt[o];
    float v = bv + lnv + bf2f(ot[o * 72 + px]) * invc;
    outp[gidx] = f2bf(v);
    s += v;
    sq = fmaf(v, v, sq);
  }
  red[0][c0w][px] = s;
  red[1][c0w][px] = sq;
  __syncthreads();
  if (t < 64) {
    int px2 = t;
    float ss = red[0][0][px2] + red[0][1][px2] + red[0][2][px2] + red[0][3][px2];
    float qq = red[1][0][px2] + red[1][1][px2] + red[1][2][px2] + red[1][3][px2];
    int xs2 = xs0 + px2;
    int xt2 = (xs2 + shift) & 127;
    int pt2 = b * HW + yt * 128 + xt2;
    float mm = ss * (1.f / 96.f);
    float var = fmaf(-mm, mm, qq * (1.f / 96.f));
    mu[pt2] = mm;
    rstd[pt2] = rsqrtf(var + 1e-5f);
  }
}

// ---------------- MFMA MLP ----------------
// 128-px tile, 4 waves, 512 blocks (2/CU). L2-load-latency bound: weight-frag
// reuse GEMM1 1:8, GEMM2 1:4; explicit prefetch arrays force deep MLP.
// NOTE: decode is built for a 512-block grid (sel = bid>>8, tile = bid&255).
// Launch with EXACTLY 512 blocks — 1024 made sel=2,3 write OOB past d_out (R4 crash).
__global__ __launch_bounds__(256, 2) void mlp_k(
    const unsigned short* __restrict__ x_l, const unsigned short* __restrict__ x_h,
    float* __restrict__ outp,
    const unsigned short* __restrict__ w1b, const float* __restrict__ b1,
    const unsigned short* __restrict__ w2b, const float* __restrict__ b2) {
  __shared__ __align__(16) unsigned char smem[51200];
  unsigned short* Xa = (unsigned short*)smem;   // [128][104] rotated groups
  unsigned short* Ha = (unsigned short*)smem;   // [128][200]
  float* Ot = (float*)smem;                     // [96][132]

  int t = threadIdx.x;
  int lane = t & 63;
  int w = rfl(t >> 6);
  int n16 = lane & 15, quad = lane >> 4;
  int sel = blockIdx.x >> 8;
  int tile = blockIdx.x & 255;
  const unsigned short* x = sel ? x_h : x_l;
  float* op = outp + (size_t)sel * (2 * CHN * HW);
  int Pb = tile * 128;
  int b = Pb >> 14, rr0 = Pb & 16383;

  // ---- stage: issue all 6 x-loads, then all 18 w1 frags + 6 biases (deep MLP),
  // then scatter x into Xa with group-rotation swizzle ----
  u16x8 xv6[6];
  int cc6[6], pp6[6];
#pragma unroll
  for (int k = 0; k < 6; ++k) {
    int i = t + k * 256;                 // 0..1535
    cc6[k] = i >> 4; pp6[k] = i & 15;    // 96 ch x 16 px-groups
    xv6[k] = ld8u(&x[((size_t)b * CHN + cc6[k]) * HW + rr0 + pp6[k] * 8]);
  }
  bf16x8 wf[18];
  float b1v6[6];
#pragma unroll
  for (int h2 = 0; h2 < 2; ++h2)
#pragma unroll
    for (int ni = 0; ni < 3; ++ni) {
      int nrow = h2 * 192 + w * 48 + ni * 16 + n16;
#pragma unroll
      for (int kk = 0; kk < 3; ++kk)
        wf[(h2 * 3 + ni) * 3 + kk] = ld8(&w1b[(size_t)nrow * 96 + kk * 32 + quad * 8]);
      b1v6[h2 * 3 + ni] = b1[nrow];
    }
#pragma unroll
  for (int k = 0; k < 6; ++k) {
    int cr = cc6[k] + 8 * pp6[k];
    if (cr >= 96) cr -= 96;
    if (cr >= 96) cr -= 96;
#pragma unroll
    for (int u = 0; u < 8; ++u) Xa[(pp6[k] * 8 + u) * 104 + cr] = xv6[k][u];
  }
  __syncthreads();

  bf16x8 af[24];
  int rotb = n16 >> 3;
#pragma unroll
  for (int mi = 0; mi < 8; ++mi)
#pragma unroll
    for (int k = 0; k < 3; ++k) {
      int gidx = k * 4 + quad + 2 * mi + rotb;
      if (gidx >= 24) gidx -= 24; else if (gidx >= 12) gidx -= 12;
      af[mi * 3 + k] = ld8(&Xa[(mi * 16 + n16) * 104 + gidx * 8]);
    }
  __syncthreads();   // Xa dead; Ha overlays

  int ph = w & 1, fh = w >> 1;
  f32x4 acc2[4][3];
#pragma unroll
  for (int g2 = 0; g2 < 4; ++g2)
#pragma unroll
    for (int ni = 0; ni < 3; ++ni) { f32x4 z = {0.f, 0.f, 0.f, 0.f}; acc2[g2][ni] = z; }

#pragma unroll
  for (int half = 0; half < 2; ++half) {
    // GEMM1: wave's 48 features x 128 px; weight frag reused over 8 mi (1:8)
#pragma unroll
    for (int ni = 0; ni < 3; ++ni) {
      f32x4 acc[8];
#pragma unroll
      for (int mi = 0; mi < 8; ++mi) { f32x4 z = {0.f, 0.f, 0.f, 0.f}; acc[mi] = z; }
#pragma unroll
      for (int kk = 0; kk < 3; ++kk) {
        bf16x8 bf = wf[(half * 3 + ni) * 3 + kk];
#pragma unroll
        for (int mi = 0; mi < 8; ++mi)
          acc[mi] = __builtin_amdgcn_mfma_f32_16x16x32_bf16(af[mi * 3 + kk], bf, acc[mi], 0, 0, 0);
      }
      int fl = w * 48 + ni * 16 + n16;
      float b1v = b1v6[half * 3 + ni];
#pragma unroll
      for (int mi = 0; mi < 8; ++mi)
#pragma unroll
        for (int r = 0; r < 4; ++r)
          Ha[(mi * 16 + quad * 4 + r) * 200 + fl] = f2bf(gelu_sig(acc[mi][r] + b1v));
    }
    __syncthreads();

    // GEMM2: wave = (ph px-half: 4 groups of 16 px, fh feat-half: 48 out-features);
    // w2 frags prefetched in batches of 9, each reused over 4 px-groups (1:4)
#pragma unroll
    for (int kc = 0; kc < 2; ++kc) {
      bf16x8 w2f[9];
#pragma unroll
      for (int kk = 0; kk < 3; ++kk)
#pragma unroll
        for (int ni = 0; ni < 3; ++ni)
          w2f[kk * 3 + ni] = ld8(&w2b[((size_t)(fh * 48 + ni * 16 + n16)) * 384 +
                                      half * 192 + (kc * 3 + kk) * 32 + quad * 8]);
#pragma unroll
      for (int kk = 0; kk < 3; ++kk) {
        int k0 = kc * 3 + kk;
        bf16x8 a2[4];
#pragma unroll
        for (int g2 = 0; g2 < 4; ++g2)
          a2[g2] = ld8(&Ha[((ph * 4 + g2) * 16 + n16) * 200 + k0 * 32 + quad * 8]);
#pragma unroll
        for (int ni = 0; ni < 3; ++ni)
#pragma unroll
          for (int g2 = 0; g2 < 4; ++g2)
            acc2[g2][ni] = __builtin_amdgcn_mfma_f32_16x16x32_bf16(a2[g2], w2f[kk * 3 + ni], acc2[g2][ni], 0, 0, 0);
      }
    }
    __syncthreads();   // Ha(half) consumed; safe for next half's GEMM1 writes / Ot overlay
  }

  // Ot overlay (Ha dead)
#pragma unroll
  for (int g2 = 0; g2 < 4; ++g2)
#pragma unroll
    for (int ni = 0; ni < 3; ++ni)
#pragma unroll
      for (int r = 0; r < 4; ++r)
        Ot[(fh * 48 + ni * 16 + n16) * 132 + (ph * 4 + g2) * 16 + quad * 4 + r] = acc2[g2][ni][r];
  __syncthreads();

#pragma unroll
  for (int k = 0; k < 12; ++k) {
    int i = t + k * 256;
    int o = i >> 5, pg = i & 31;
    size_t gbase = ((size_t)b * CHN + o) * HW + rr0 + pg * 4;
    ushort4 xv = *(const ushort4*)&x[gbase];
    float4 ov = *(const float4*)&Ot[o * 132 + pg * 4];
    float bb = b2[o];
    float4 res;
    res.x = bf2f(xv.x) + ov.x + bb;
    res.y = bf2f(xv.y) + ov.y + bb;
    res.z = bf2f(xv.z) + ov.z + bb;
    res.w = bf2f(xv.w) + ov.w + bb;
    *(float4*)&op[gbase] = res;
  }
}

extern "C" void kernel_launch(void* const* d_in, const int* in_sizes, int n_in,
                              void* d_out, int out_size, void* d_ws, size_t ws_size,
                              hipStream_t stream) {
  (void)in_sizes; (void)n_in; (void)out_size; (void)ws_size;
  const float* low   = (const float*)d_in[0];
  const float* high  = (const float*)d_in[1];
  const float* ln1_g = (const float*)d_in[2];
  const float* ln1_b = (const float*)d_in[3];
  const float* ln2_g = (const float*)d_in[4];
  const float* ln2_b = (const float*)d_in[5];
  const float* se_w1 = (const float*)d_in[6];
  const float* se_w2 = (const float*)d_in[7];
  const float* wq_l  = (const float*)d_in[8];
  const float* wk_h  = (const float*)d_in[9];
  const float* wv_h  = (const float*)d_in[10];
  const float* wq_h  = (const float*)d_in[11];
  const float* wk_l  = (const float*)d_in[12];
  const float* wv_l  = (const float*)d_in[13];
  const float* wp_l  = (const float*)d_in[14];
  const float* wp_h  = (const float*)d_in[15];
  const float* mw1   = (const float*)d_in[16];
  const float* mb1   = (const float*)d_in[17];
  const float* mw2   = (const float*)d_in[18];
  const float* mb2   = (const float*)d_in[19];

  // ws layout, ~98.4 MB total (poison-fill WRITE_SIZE shows ws = 256 MiB)
  float* ws = (float*)d_ws;
  unsigned short* w1b = (unsigned short*)ws;
  unsigned short* w2b = w1b + 36864;
  unsigned short* wqb = w2b + 36864;
  unsigned short* wpb = wqb + 55296;                  // front total 147456 shorts = 73728 floats
  float* mu_l  = ws + 73728;
  float* rs_l  = mu_l + 32768;
  float* mu_h  = rs_l + 32768;
  float* rs_h  = mu_h + 32768;
  float* poolb = rs_h + 32768;
  float* s_se  = poolb + 256;
  unsigned short* low1b  = (unsigned short*)(s_se + 256);
  unsigned short* high1b = low1b + 3145728;
  unsigned short* qkv    = high1b + 3145728;          // 18874368 shorts
  unsigned short* Owin   = qkv + 18874368;            // 23617536 shorts (2 dirs x 2 b)

  cvt_k<<<216, 256, 0, stream>>>(mw1, mw2, wq_l, wk_h, wv_h, wq_h, wk_l, wv_l,
                                 wp_l, wp_h, w1b, w2b, wqb, wpb);

  ln2_k<float><<<64, 256, 0, stream>>>(low, high, mu_l, rs_l, mu_h, rs_h);

  for (int pass = 0; pass < 2; ++pass) {
    const float* g  = pass ? ln2_g : ln1_g;
    const float* bt = pass ? ln2_b : ln1_b;
    int shift = pass ? 4 : 0;

    if (pass == 0) {
      pool_k<float><<<192, 256, 0, stream>>>(high, mu_h, rs_h, g, bt, poolb);
      se_k<<<1, 256, 0, stream>>>(poolb, se_w1, se_w2, s_se);
      proj_k<float><<<512, 256, 0, stream>>>(low, high, mu_l, rs_l, mu_h, rs_h,
                                             g, bt, s_se, wqb, qkv);
      attn_k<<<2 * 1922, 256, 0, stream>>>(qkv, Owin, shift);
      combine_k<float><<<1024, 256, 0, stream>>>(low, high, low1b, high1b, Owin,
                                                 mu_l, rs_l, mu_h, rs_h,
                                                 g, bt, wpb, shift);
    } else {
      pool_k<unsigned short><<<192, 256, 0, stream>>>(high1b, mu_h, rs_h, g, bt, poolb);
      se_k<<<1, 256, 0, stream>>>(poolb, se_w1, se_w2, s_se);
      proj_k<unsigned short><<<512, 256, 0, stream>>>(low1b, high1b, mu_l, rs_l, mu_h, rs_h,
                                                      g, bt, s_se, wqb, qkv);
      attn_k<<<2 * 1922, 256, 0, stream>>>(qkv, Owin, shift);
      combine_k<unsigned short><<<1024, 256, 0, stream>>>(low1b, high1b, low1b, high1b, Owin,
                                                          mu_l, rs_l, mu_h, rs_h,
                                                          g, bt, wpb, shift);
    }
  }
  mlp_k<<<512, 256, 0, stream>>>(low1b, high1b, (float*)d_out, w1b, mb1, w2b, mb2);
}

// Round 11
// 324.378 us; speedup vs baseline: 1.4486x; 1.4486x over previous
//
#include <hip/hip_runtime.h>
#include <math.h>

#define CHN 96
#define HW 16384
#define NWIN 31
#define SCALE_F 0.20412414523193154f
#define SCALE_L2 0.294488893f   // SCALE_F * log2(e): exp(s*SCALE) == exp2(s*SCALE_L2)

typedef __attribute__((ext_vector_type(8))) __bf16 bf16x8;
typedef __attribute__((ext_vector_type(4))) float f32x4;
typedef __attribute__((ext_vector_type(8))) unsigned short u16x8;

__device__ __forceinline__ int rfl(int v) { return __builtin_amdgcn_readfirstlane(v); }

__device__ __forceinline__ unsigned short f2bf(float f) {
  union { float f; unsigned u; } v; v.f = f;
  unsigned r = v.u + 0x7fffu + ((v.u >> 16) & 1u);
  return (unsigned short)(r >> 16);
}
__device__ __forceinline__ float bf2f(unsigned short h) {
  union { unsigned u; float f; } v; v.u = ((unsigned)h) << 16;
  return v.f;
}
__device__ __forceinline__ float fexp2(float x) {
#if __has_builtin(__builtin_amdgcn_exp2f)
  return __builtin_amdgcn_exp2f(x);
#else
  return __expf(x * 0.6931471806f);
#endif
}
__device__ __forceinline__ float ldv(const float* p, size_t i) { return p[i]; }
__device__ __forceinline__ float ldv(const unsigned short* p, size_t i) { return bf2f(p[i]); }
__device__ __forceinline__ bf16x8 ld8(const unsigned short* p) {
  return *(const bf16x8*)__builtin_assume_aligned(p, 16);
}
__device__ __forceinline__ u16x8 ld8u(const unsigned short* p) {
  return *(const u16x8*)__builtin_assume_aligned(p, 16);
}
__device__ __forceinline__ bf16x8 zf8() {
  union { unsigned long long u[2]; bf16x8 v; } z;
  z.u[0] = 0ull; z.u[1] = 0ull;
  return z.v;
}
__device__ __forceinline__ bf16x8 onesf8() {
  union { unsigned short s[8]; bf16x8 v; } o;
#pragma unroll
  for (int i = 0; i < 8; ++i) o.s[i] = 0x3F80;  // bf16 1.0
  return o.v;
}
// vector load helpers: 8 / 4 floats from fp32 or bf16 source
__device__ __forceinline__ void ld8f(const float* p, float* o) {
  float4 a = *(const float4*)__builtin_assume_aligned(p, 16);
  float4 b = *(const float4*)__builtin_assume_aligned(p + 4, 16);
  o[0] = a.x; o[1] = a.y; o[2] = a.z; o[3] = a.w;
  o[4] = b.x; o[5] = b.y; o[6] = b.z; o[7] = b.w;
}
__device__ __forceinline__ void ld8f(const unsigned short* p, float* o) {
  u16x8 v = ld8u(p);
#pragma unroll
  for (int u = 0; u < 8; ++u) o[u] = bf2f(v[u]);
}
__device__ __forceinline__ void ld4f(const float* p, float* o) {
  float4 a = *(const float4*)__builtin_assume_aligned(p, 16);
  o[0] = a.x; o[1] = a.y; o[2] = a.z; o[3] = a.w;
}
__device__ __forceinline__ void ld4f(const unsigned short* p, float* o) {
  ushort4 v = *(const ushort4*)__builtin_assume_aligned(p, 8);
  o[0] = bf2f(v.x); o[1] = bf2f(v.y); o[2] = bf2f(v.z); o[3] = bf2f(v.w);
}

// GELU via x*sigmoid(1.702x); |err vs exact| <= ~0.02 (within absmax budget)
__device__ __forceinline__ float gelu_sig(float x) {
  return x * __builtin_amdgcn_rcpf(1.f + __expf(-1.702f * x));
}

// ---------------- LN stats (pass 0 only), 4 px/thread vectorized, grid 64 ----------------
template <typename T>
__global__ __launch_bounds__(256) void ln2_k(const T* __restrict__ xl, const T* __restrict__ xh,
                                             float* __restrict__ mu_l, float* __restrict__ rs_l,
                                             float* __restrict__ mu_h, float* __restrict__ rs_h) {
  int which = blockIdx.x >> 5;           // 32 blocks per tensor
  int idx = (blockIdx.x & 31) * 256 + threadIdx.x;   // 0..8191
  int pix0 = idx * 4;                    // 0..32764
  const T* xt = which ? xh : xl;
  float* mu = which ? mu_h : mu_l;
  float* rstd = which ? rs_h : rs_l;
  int b = pix0 >> 14, p = pix0 & 16383;
  const T* xp = xt + (size_t)b * CHN * HW + p;
  float s[4] = {0.f, 0.f, 0.f, 0.f}, s2[4] = {0.f, 0.f, 0.f, 0.f};
#pragma unroll 8
  for (int c = 0; c < CHN; ++c) {
    float v4[4];
    ld4f(xp + (size_t)c * HW, v4);
#pragma unroll
    for (int j = 0; j < 4; ++j) {
      s[j] += v4[j];
      s2[j] = fmaf(v4[j], v4[j], s2[j]);
    }
  }
  float4 mo, ro;
  float m0 = s[0] * (1.f / 96.f), m1 = s[1] * (1.f / 96.f);
  float m2 = s[2] * (1.f / 96.f), m3 = s[3] * (1.f / 96.f);
  mo.x = m0; mo.y = m1; mo.z = m2; mo.w = m3;
  ro.x = rsqrtf(fmaf(-m0, m0, s2[0] * (1.f / 96.f)) + 1e-5f);
  ro.y = rsqrtf(fmaf(-m1, m1, s2[1] * (1.f / 96.f)) + 1e-5f);
  ro.z = rsqrtf(fmaf(-m2, m2, s2[2] * (1.f / 96.f)) + 1e-5f);
  ro.w = rsqrtf(fmaf(-m3, m3, s2[3] * (1.f / 96.f)) + 1e-5f);
  *(float4*)&mu[pix0] = mo;
  *(float4*)&rstd[pix0] = ro;
}

// ---------------- SE pool (4 px/iter vectorized) ----------------
template <typename T>
__global__ __launch_bounds__(256) void pool_k(const T* __restrict__ x,
                                              const float* __restrict__ mu,
                                              const float* __restrict__ rstd,
                                              const float* __restrict__ g,
                                              const float* __restrict__ bt,
                                              float* __restrict__ pool) {
  int blk = blockIdx.x;
  int b = blk / CHN, c = blk % CHN;
  const T* xp = x + (size_t)(b * CHN + c) * HW;
  const float* mup = mu + b * HW;
  const float* rp = rstd + b * HW;
  int t = threadIdx.x;
  float s = 0.f;
  for (int p0 = t * 4; p0 < HW; p0 += 1024) {
    float v4[4];
    ld4f(xp + p0, v4);
    float4 m4 = *(const float4*)&mup[p0];
    float4 r4 = *(const float4*)&rp[p0];
    s += (v4[0] - m4.x) * r4.x + (v4[1] - m4.y) * r4.y +
         (v4[2] - m4.z) * r4.z + (v4[3] - m4.w) * r4.w;
  }
  __shared__ float red[256];
  red[t] = s;
  __syncthreads();
  for (int k = 128; k > 0; k >>= 1) {
    if (t < k) red[t] += red[t + k];
    __syncthreads();
  }
  if (t == 0) pool[blk] = g[c] * (red[0] * (1.f / 16384.f)) + bt[c];
}

// ---------------- SE gate ----------------
__global__ __launch_bounds__(256) void se_k(const float* __restrict__ pool,
                                            const float* __restrict__ w1,
                                            const float* __restrict__ w2,
                                            float* __restrict__ s_se) {
  int t = threadIdx.x;
  if (t >= 2 * CHN) return;
  int b = t / CHN, c = t % CHN;
  int i = c >> 5, cl = c & 31;
  const float* pg = pool + b * CHN + i * 32;
  const float* w1p = w1 + i * 64;
  float z0 = 0.f, z1 = 0.f;
#pragma unroll 8
  for (int k = 0; k < 32; ++k) {
    float p = pg[k];
    z0 = fmaf(p, w1p[k], z0);
    z1 = fmaf(p, w1p[32 + k], z1);
  }
  z0 = fmaxf(z0, 0.f);
  z1 = fmaxf(z1, 0.f);
  float a = z0 * w2[i * 64 + cl * 2] + z1 * w2[i * 64 + cl * 2 + 1];
  s_se[t] = 1.f / (1.f + __expf(-a));
}

// ---------------- weight convert fp32 -> bf16 ----------------
__global__ __launch_bounds__(256) void cvt_k(const float* __restrict__ w1,
                                             const float* __restrict__ w2,
                                             const float* __restrict__ p0,
                                             const float* __restrict__ p1,
                                             const float* __restrict__ p2,
                                             const float* __restrict__ p3,
                                             const float* __restrict__ p4,
                                             const float* __restrict__ p5,
                                             const float* __restrict__ q0,
                                             const float* __restrict__ q1,
                                             unsigned short* __restrict__ w1b,
                                             unsigned short* __restrict__ w2b,
                                             unsigned short* __restrict__ wqb,
                                             unsigned short* __restrict__ wpb) {
  int i = blockIdx.x * 256 + threadIdx.x;
  if (i < 36864) {
    w1b[i] = f2bf(w1[i]);
    w2b[i] = f2bf(w2[i]);
  }
  if (i < 55296) {
    int tt = i / 9216, rem = i - tt * 9216;
    const float* ps[6] = {p0, p1, p2, p3, p4, p5};
    wqb[i] = f2bf(ps[tt][rem]);
  }
  if (i < 18432) {
    wpb[i] = f2bf(i < 9216 ? q0[i] : q1[i - 9216]);
  }
}

// ---------------- MFMA full-image QKV projection ----------------
// qkv slots [t][b]; Q/K (t=0,1,3,4) pixel-major [pix][96]; V (t=2,5) channel-major [c][HW].
// Staging: thread owns (channel, fixed 8-px group) -> 8-px vector loads, stats hoisted.
// LDS staging uses group-rotation swizzle: col' = (c + 8*(row>>3)) mod 96 so the
// pixel-major scatter writes spread over all 8 16B-slots mod 128 (was 16-way conflict).
template <typename T>
__global__ __launch_bounds__(256, 3) void proj_k(
    const T* __restrict__ lowp, const T* __restrict__ highp,
    const float* __restrict__ mu_l, const float* __restrict__ rs_l,
    const float* __restrict__ mu_h, const float* __restrict__ rs_h,
    const float* __restrict__ g, const float* __restrict__ bt,
    const float* __restrict__ s_se,
    const unsigned short* __restrict__ wqb,
    unsigned short* __restrict__ qkv) {
  __shared__ __align__(16) unsigned short sh[13312];  // Xl[64*104] | Xh[64*104]; later tb[4][32*104]
  unsigned short* Xl = sh;
  unsigned short* Xh = sh + 6656;
  int t = threadIdx.x;
  int lane = t & 63;
  int w = rfl(t >> 6);
  int n16 = lane & 15, quad = lane >> 4;
  int tile = blockIdx.x;
  int Pb = tile * 64;
  int b = Pb >> 14, rr0 = Pb & 16383;

  // ---- stage: thread's fixed 8 pixels = rr0 + (t&7)*8 .. +7 ----
  {
    int pg = t & 7;
    float mul8[8], rsl8[8], muh8[8], rsh8[8];
    ld8f(mu_l + (size_t)b * HW + rr0 + pg * 8, mul8);
    ld8f(rs_l + (size_t)b * HW + rr0 + pg * 8, rsl8);
    ld8f(mu_h + (size_t)b * HW + rr0 + pg * 8, muh8);
    ld8f(rs_h + (size_t)b * HW + rr0 + pg * 8, rsh8);
#pragma unroll
    for (int k = 0; k < 3; ++k) {
      int c = (t + k * 256) >> 3;
      float gc = g[c], bc = bt[c], sc = s_se[b * CHN + c];
      float xl8[8], xh8[8];
      ld8f(lowp + (size_t)(b * CHN + c) * HW + rr0 + pg * 8, xl8);
      ld8f(highp + (size_t)(b * CHN + c) * HW + rr0 + pg * 8, xh8);
      int cr = c + pg * 8; if (cr >= 96) cr -= 96;   // rotated col (row>>3 == pg)
#pragma unroll
      for (int u = 0; u < 8; ++u) {
        int px = pg * 8 + u;
        Xl[px * 104 + cr] = f2bf((xl8[u] - mul8[u]) * rsl8[u] * gc + bc);
        Xh[px * 104 + cr] = f2bf(((xh8[u] - muh8[u]) * rsh8[u] * gc + bc) * sc);
      }
    }
  }
  __syncthreads();

  // register-cache A-frags for BOTH the main (pixel-major) tensor and the V tensor
  int tmain = (0x4310 >> (4 * w)) & 15;          // w: 0->t0, 1->t1, 2->t3, 3->t4
  const unsigned short* Xm = (w == 0 || w == 3) ? Xl : Xh;
  const unsigned short* Xv = (w < 2) ? Xh : Xl;
  bf16x8 af[12], av[12];
  int rotb = n16 >> 3;
#pragma unroll
  for (int mi = 0; mi < 4; ++mi)
#pragma unroll
    for (int k = 0; k < 3; ++k) {
      int gidx = k * 4 + quad + 2 * mi + rotb; if (gidx >= 12) gidx -= 12;
      af[mi * 3 + k] = ld8(&Xm[(mi * 16 + n16) * 104 + gidx * 8]);
      av[mi * 3 + k] = ld8(&Xv[(mi * 16 + n16) * 104 + gidx * 8]);
    }
  __syncthreads();   // X dead; tb overlays

  unsigned short* tw = sh + w * 3328;
#pragma unroll
  for (int half = 0; half < 2; ++half) {
#pragma unroll
    for (int ni = 0; ni < 6; ++ni) {
      f32x4 a0 = {0.f, 0.f, 0.f, 0.f}, a1 = {0.f, 0.f, 0.f, 0.f};
#pragma unroll
      for (int k = 0; k < 3; ++k) {
        bf16x8 bf = ld8(&wqb[((size_t)tmain * 96 + ni * 16 + n16) * 96 + k * 32 + quad * 8]);
        a0 = __builtin_amdgcn_mfma_f32_16x16x32_bf16(af[(half * 2 + 0) * 3 + k], bf, a0, 0, 0, 0);
        a1 = __builtin_amdgcn_mfma_f32_16x16x32_bf16(af[(half * 2 + 1) * 3 + k], bf, a1, 0, 0, 0);
      }
#pragma unroll
      for (int r = 0; r < 4; ++r) {
        tw[(quad * 4 + r) * 104 + ni * 16 + n16] = f2bf(a0[r]);
        tw[(16 + quad * 4 + r) * 104 + ni * 16 + n16] = f2bf(a1[r]);
      }
    }
    // wave-local readout (per-wave DS ops in-order; no barrier)
#pragma unroll
    for (int c6 = 0; c6 < 6; ++c6) {
      int chunk = lane + 64 * c6;
      int pl2 = chunk / 12, kb2 = chunk - pl2 * 12;
      u16x8 v = ld8u(&tw[pl2 * 104 + kb2 * 8]);
      size_t pix = (size_t)rr0 + half * 32 + pl2;
      *(u16x8*)&qkv[((size_t)(tmain * 2 + b) * HW + pix) * 96 + kb2 * 8] = v;
    }
  }

  // V units from register-cached av
  int tv = (w < 2) ? 2 : 5;
  int nbase = (w & 1) * 3;
#pragma unroll
  for (int jj = 0; jj < 3; ++jj) {
    int ni = nbase + jj;
    f32x4 acc[4];
#pragma unroll
    for (int mi = 0; mi < 4; ++mi) { f32x4 z = {0.f, 0.f, 0.f, 0.f}; acc[mi] = z; }
#pragma unroll
    for (int k = 0; k < 3; ++k) {
      bf16x8 bf = ld8(&wqb[((size_t)tv * 96 + ni * 16 + n16) * 96 + k * 32 + quad * 8]);
#pragma unroll
      for (int mi = 0; mi < 4; ++mi)
        acc[mi] = __builtin_amdgcn_mfma_f32_16x16x32_bf16(av[mi * 3 + k], bf, acc[mi], 0, 0, 0);
    }
    int feat = ni * 16 + n16;
    size_t rowbase = ((size_t)(tv * 2 + b) * CHN + feat) * HW + rr0;
#pragma unroll
    for (int mi = 0; mi < 4; ++mi) {
      ushort4 o4;
      o4.x = f2bf(acc[mi][0]);
      o4.y = f2bf(acc[mi][1]);
      o4.z = f2bf(acc[mi][2]);
      o4.w = f2bf(acc[mi][3]);
      *(ushort4*)&qkv[rowbase + mi * 16 + quad * 4] = o4;
    }
  }
}

// ---------------- MFMA window attention (both dirs fused in one launch) ----------------
// grid = 2 dirs x 2 batches x 961 windows = 3844 blocks. Owin slot (dir*2 + b).
// XCD swizzle: 3844 % 8 = 4 -> bijective chunked variant (q=480, r=4):
//   chunk start = x<4 ? x*481 : 1924 + (x-4)*480   (x = bid0 & 7, y = bid0 >> 3)
// [R7 ERRATA: naive remap at nwg=3844 skipped half the windows; absmax was the tell.]
// [R9 ERRATA: direct per-lane V loads from channel-major global = 8B gather with
//  lanes 32KB apart -> FETCH 155MB + 334MB write amplification, 2.7x slower. V MUST
//  be staged cooperatively through LDS; coalescing is a cross-lane property.]
// T14 staging: issue all 6 V-loads + 8 Q/K-loads before any ds_write.
// Softmax normalization via extra MFMA against ones-frag; no-max softmax.
__global__ __launch_bounds__(256, 5) void attn_k(
    const unsigned short* __restrict__ qkv,
    unsigned short* __restrict__ Owin, int shift) {
  __shared__ __align__(16) unsigned short shb[16128];  // Vs[96*72]=6912 | P32[4*64*36]=9216
  unsigned short* Vs = shb;                            // later overlaid by Os[64*104]
  unsigned short* P32 = shb + 6912;
  unsigned short* Os = shb;

  int bid0 = blockIdx.x;
  int x8 = bid0 & 7, y8 = bid0 >> 3;
  int bid = (x8 < 4 ? x8 * 481 : 1924 + (x8 - 4) * 480) + y8;  // bijective on [0,3844)
  int dir = bid / 1922;
  int rem = bid - dir * 1922;
  int b = rem / 961;
  int win = rem - b * 961;
  int wy = win / NWIN, wx = win % NWIN;
  int t = threadIdx.x;
  int lane = t & 63;
  int h = rfl(t >> 6);
  int n16 = lane & 15, quad = lane >> 4;

  // ---- T14: issue ALL global loads (V x6, Q x4, K x4) before any LDS write ----
  ushort4 vv[6];
  int vdst[6];
  {
    const unsigned short* vbase = qkv + (size_t)((dir * 3 + 2) * 2 + b) * CHN * HW;
#pragma unroll
    for (int k = 0; k < 6; ++k) {
      int i = t + k * 256;
      int c = i >> 4, ry = (i >> 1) & 7, hx = i & 1;
      int gy = (wy * 4 + ry + shift) & 127;
      int gx = (wx * 4 + hx * 4 + shift) & 127;
      vv[k] = *(const ushort4*)(vbase + (size_t)c * HW + gy * 128 + gx);
      vdst[k] = c * 72 + ry * 8 + hx * 4;
    }
  }

  bf16x8 qa[4], kb4[4];
  {
    const unsigned short* qpm = qkv + (size_t)((dir * 3 + 0) * 2 + b) * CHN * HW;
    const unsigned short* kpm = qkv + (size_t)((dir * 3 + 1) * 2 + b) * CHN * HW;
    if (quad < 3) {
#pragma unroll
      for (int ni = 0; ni < 4; ++ni) {
        int n = ni * 16 + n16;
        int gy = (wy * 4 + (n >> 3) + shift) & 127;
        int gx = (wx * 4 + (n & 7) + shift) & 127;
        size_t pix = (size_t)gy * 128 + gx;
        qa[ni] = ld8(&qpm[pix * 96 + h * 24 + quad * 8]);
        kb4[ni] = ld8(&kpm[pix * 96 + h * 24 + quad * 8]);
      }
    } else {
#pragma unroll
      for (int ni = 0; ni < 4; ++ni) { qa[ni] = zf8(); kb4[ni] = zf8(); }
    }
  }

  // commit V to LDS (loads above already in flight)
#pragma unroll
  for (int k = 0; k < 6; ++k) *(ushort4*)&Vs[vdst[k]] = vv[k];
  __syncthreads();

  const int hP = h * (64 * 36);

  f32x4 sa[4][4];
#pragma unroll
  for (int ni = 0; ni < 4; ++ni)
#pragma unroll
    for (int mi = 0; mi < 4; ++mi) {
      f32x4 z = {0.f, 0.f, 0.f, 0.f};
      sa[ni][mi] = __builtin_amdgcn_mfma_f32_16x16x32_bf16(qa[ni], kb4[mi], z, 0, 0, 0);
    }

  // unnormalized exponentials (no-max softmax; scores bounded)
#pragma unroll
  for (int ni = 0; ni < 4; ++ni)
#pragma unroll
    for (int mi = 0; mi < 4; ++mi)
#pragma unroll
      for (int r = 0; r < 4; ++r)
        sa[ni][mi][r] = fexp2(sa[ni][mi][r] * SCALE_L2);

  const bf16x8 ones = onesf8();
  f32x4 oa[4][2];
  f32x4 sacc[4];
#pragma unroll
  for (int ni = 0; ni < 4; ++ni) {
    f32x4 z = {0.f, 0.f, 0.f, 0.f};
    oa[ni][0] = z; oa[ni][1] = z; sacc[ni] = z;
  }
#pragma unroll
  for (int s = 0; s < 2; ++s) {
#pragma unroll
    for (int ni = 0; ni < 4; ++ni)
#pragma unroll
      for (int r = 0; r < 4; ++r) {
#pragma unroll
        for (int mm = 0; mm < 2; ++mm) {
          int mi = s * 2 + mm;
          P32[hP + (ni * 16 + quad * 4 + r) * 36 + mm * 16 + n16] = f2bf(sa[ni][mi][r]);
        }
      }
    bf16x8 pa[4];
#pragma unroll
    for (int ni = 0; ni < 4; ++ni) pa[ni] = ld8(&P32[hP + (ni * 16 + n16) * 36 + quad * 8]);
    bf16x8 vb0 = ld8(&Vs[(h * 24 + n16) * 72 + s * 32 + quad * 8]);
    bf16x8 vb1 = (n16 < 8) ? ld8(&Vs[(h * 24 + 16 + n16) * 72 + s * 32 + quad * 8]) : zf8();
#pragma unroll
    for (int ni = 0; ni < 4; ++ni) {
      oa[ni][0] = __builtin_amdgcn_mfma_f32_16x16x32_bf16(pa[ni], vb0, oa[ni][0], 0, 0, 0);
      oa[ni][1] = __builtin_amdgcn_mfma_f32_16x16x32_bf16(pa[ni], vb1, oa[ni][1], 0, 0, 0);
      sacc[ni] = __builtin_amdgcn_mfma_f32_16x16x32_bf16(pa[ni], ones, sacc[ni], 0, 0, 0);
    }
  }

  // normalize O by MFMA-computed row sums (same accumulator layout: row = quad*4+r)
#pragma unroll
  for (int ni = 0; ni < 4; ++ni)
#pragma unroll
    for (int r = 0; r < 4; ++r) {
      float inv = __builtin_amdgcn_rcpf(sacc[ni][r]);
      oa[ni][0][r] *= inv;
      oa[ni][1][r] *= inv;
    }
  __syncthreads();   // Vs dead; Os overlays

  // stage O -> Os[px][96] (pad 104), then coalesced 16B stores
#pragma unroll
  for (int ni = 0; ni < 4; ++ni)
#pragma unroll
    for (int r = 0; r < 4; ++r) {
      int n = ni * 16 + quad * 4 + r;
      Os[n * 104 + h * 24 + n16] = f2bf(oa[ni][0][r]);
      if (n16 < 8) Os[n * 104 + h * 24 + 16 + n16] = f2bf(oa[ni][1][r]);
    }
  __syncthreads();

  {
    unsigned short* obase = Owin + (size_t)((dir * 2 + b) * 961 + win) * 64 * CHN;
#pragma unroll
    for (int k = 0; k < 3; ++k) {
      int i = t + k * 256;               // 0..767
      int px = i / 12, cb = i - px * 12;
      u16x8 v = ld8u(&Os[px * 104 + cb * 8]);
      *(u16x8*)&obase[px * CHN + cb * 8] = v;
    }
  }
}

// ---------------- MFMA combine + fused next-pass LN stats (low+high fused) ----------------
// grid 1024; XCD-chunk swizzle (1024 = 8*128, divisible -> simple form is bijective).
// sel picks (low, dir0) vs (high, dir1) stream.
template <typename T>
__global__ __launch_bounds__(256) void combine_k(
    const T* __restrict__ base_l, const T* __restrict__ base_h,
    unsigned short* __restrict__ out_l, unsigned short* __restrict__ out_h,
    const unsigned short* __restrict__ Owin,
    float* __restrict__ mu_lp, float* __restrict__ rs_lp,
    float* __restrict__ mu_hp, float* __restrict__ rs_hp,
    const float* __restrict__ g, const float* __restrict__ bt,
    const unsigned short* __restrict__ wpb2, int shift) {
  __shared__ __align__(16) unsigned short sb[96 * 72];   // at [64][104] then ot [96][72]
  __shared__ float red[2][4][64];
  unsigned short* at = sb;
  unsigned short* ot = sb;
  int t = threadIdx.x;
  int lane = t & 63;
  int w = rfl(t >> 6);
  int n16 = lane & 15, quad = lane >> 4;
  int wg = (blockIdx.x & 7) * 128 + (blockIdx.x >> 3);   // bijective XCD-chunk swizzle
  int sel = wg >> 9;
  int tile = wg & 511;                   // 0..511
  const T* base = sel ? base_h : base_l;
  unsigned short* outp = sel ? out_h : out_l;
  float* mu = sel ? mu_hp : mu_lp;
  float* rstd = sel ? rs_hp : rs_lp;
  const unsigned short* wpb = wpb2 + sel * 9216;

#pragma unroll
  for (int k = 0; k < 3; ++k) {
    int i = t + k * 256;
    int px = i / 12, cb = i - px * 12;
    int Ps = tile * 64 + px;
    int b = Ps >> 14, rem = Ps & 16383;
    int ys = rem >> 7, xs = rem & 127;
    int wyh = ys >> 2, wxh = xs >> 2;
    float acc[8];
#pragma unroll
    for (int u = 0; u < 8; ++u) acc[u] = 0.f;
    for (int dy = 0; dy < 2; ++dy) {
      int wyc = wyh - 1 + dy;
      if ((unsigned)wyc > 30u) continue;
      int py = ys - wyc * 4;
      for (int dx = 0; dx < 2; ++dx) {
        int wxc = wxh - 1 + dx;
        if ((unsigned)wxc > 30u) continue;
        int pxl = xs - wxc * 4;
        size_t o = ((size_t)((sel * 2 + b) * 961 + wyc * 31 + wxc) * 64 + py * 8 + pxl) * CHN + cb * 8;
        u16x8 v = ld8u(&Owin[o]);
#pragma unroll
        for (int u = 0; u < 8; ++u) acc[u] += bf2f(v[u]);
      }
    }
    union { u16x8 v; unsigned short s[8]; } pk;
#pragma unroll
    for (int u = 0; u < 8; ++u) pk.s[u] = f2bf(acc[u]);
    *(u16x8*)&at[px * 104 + cb * 8] = pk.v;
  }
  __syncthreads();

  bf16x8 af[3];
#pragma unroll
  for (int k = 0; k < 3; ++k)
    af[k] = ld8(&at[(w * 16 + n16) * 104 + k * 32 + quad * 8]);

  f32x4 acc6[6];
#pragma unroll
  for (int ni = 0; ni < 6; ++ni) {
    f32x4 z = {0.f, 0.f, 0.f, 0.f};
    acc6[ni] = z;
#pragma unroll
    for (int k = 0; k < 3; ++k) {
      bf16x8 bf = ld8(&wpb[(ni * 16 + n16) * 96 + k * 32 + quad * 8]);
      acc6[ni] = __builtin_amdgcn_mfma_f32_16x16x32_bf16(af[k], bf, acc6[ni], 0, 0, 0);
    }
  }
  __syncthreads();

#pragma unroll
  for (int ni = 0; ni < 6; ++ni)
#pragma unroll
    for (int r = 0; r < 4; ++r)
      ot[(ni * 16 + n16) * 72 + w * 16 + quad * 4 + r] = f2bf(acc6[ni][r]);
  __syncthreads();

  int Ps0 = tile * 64;
  int b = Ps0 >> 14, rem0 = Ps0 & 16383;
  int ys = rem0 >> 7, xs0 = rem0 & 127;
  int yt = (ys + shift) & 127;
  float icy = (ys >= 4 && ys <= 123) ? 0.5f : 1.f;
  int px = t & 63, c0w = t >> 6;
  int xs = xs0 + px;
  int xt = (xs + shift) & 127;
  float icx = (xs >= 4 && xs <= 123) ? 0.5f : 1.f;
  float invc = icy * icx;
  int pt = b * HW + yt * 128 + xt;
  float m = mu[pt], rs = rstd[pt];
  size_t pixoff = (size_t)yt * 128 + xt;
  float s = 0.f, sq = 0.f;
#pragma unroll
  for (int k = 0; k < 24; ++k) {
    int o = c0w + 4 * k;
    size_t gidx = ((size_t)b * CHN + o) * HW + pixoff;
    float bv = ldv(base, gidx);
    float lnv = (bv - m) * rs * g[o] + bt[o];
    float v = bv + lnv + bf2f(ot[o * 72 + px]) * invc;
    outp[gidx] = f2bf(v);
    s += v;
    sq = fmaf(v, v, sq);
  }
  red[0][c0w][px] = s;
  red[1][c0w][px] = sq;
  __syncthreads();
  if (t < 64) {
    int px2 = t;
    float ss = red[0][0][px2] + red[0][1][px2] + red[0][2][px2] + red[0][3][px2];
    float qq = red[1][0][px2] + red[1][1][px2] + red[1][2][px2] + red[1][3][px2];
    int xs2 = xs0 + px2;
    int xt2 = (xs2 + shift) & 127;
    int pt2 = b * HW + yt * 128 + xt2;
    float mm = ss * (1.f / 96.f);
    float var = fmaf(-mm, mm, qq * (1.f / 96.f));
    mu[pt2] = mm;
    rstd[pt2] = rsqrtf(var + 1e-5f);
  }
}

// ---------------- MFMA MLP ----------------
// 128-px tile, 4 waves, 512 blocks (2/CU). L2-load-latency bound: weight-frag
// reuse GEMM1 1:8, GEMM2 1:4; explicit prefetch arrays force deep MLP.
// NOTE: decode is built for a 512-block grid (sel = bid>>8, tile = bid&255).
// Launch with EXACTLY 512 blocks — 1024 made sel=2,3 write OOB past d_out (R4 crash).
__global__ __launch_bounds__(256, 2) void mlp_k(
    const unsigned short* __restrict__ x_l, const unsigned short* __restrict__ x_h,
    float* __restrict__ outp,
    const unsigned short* __restrict__ w1b, const float* __restrict__ b1,
    const unsigned short* __restrict__ w2b, const float* __restrict__ b2) {
  __shared__ __align__(16) unsigned char smem[51200];
  unsigned short* Xa = (unsigned short*)smem;   // [128][104] rotated groups
  unsigned short* Ha = (unsigned short*)smem;   // [128][200]
  float* Ot = (float*)smem;                     // [96][132]

  int t = threadIdx.x;
  int lane = t & 63;
  int w = rfl(t >> 6);
  int n16 = lane & 15, quad = lane >> 4;
  int sel = blockIdx.x >> 8;
  int tile = blockIdx.x & 255;
  const unsigned short* x = sel ? x_h : x_l;
  float* op = outp + (size_t)sel * (2 * CHN * HW);
  int Pb = tile * 128;
  int b = Pb >> 14, rr0 = Pb & 16383;

  // ---- stage: issue all 6 x-loads, then all 18 w1 frags + 6 biases (deep MLP),
  // then scatter x into Xa with group-rotation swizzle ----
  u16x8 xv6[6];
  int cc6[6], pp6[6];
#pragma unroll
  for (int k = 0; k < 6; ++k) {
    int i = t + k * 256;                 // 0..1535
    cc6[k] = i >> 4; pp6[k] = i & 15;    // 96 ch x 16 px-groups
    xv6[k] = ld8u(&x[((size_t)b * CHN + cc6[k]) * HW + rr0 + pp6[k] * 8]);
  }
  bf16x8 wf[18];
  float b1v6[6];
#pragma unroll
  for (int h2 = 0; h2 < 2; ++h2)
#pragma unroll
    for (int ni = 0; ni < 3; ++ni) {
      int nrow = h2 * 192 + w * 48 + ni * 16 + n16;
#pragma unroll
      for (int kk = 0; kk < 3; ++kk)
        wf[(h2 * 3 + ni) * 3 + kk] = ld8(&w1b[(size_t)nrow * 96 + kk * 32 + quad * 8]);
      b1v6[h2 * 3 + ni] = b1[nrow];
    }
#pragma unroll
  for (int k = 0; k < 6; ++k) {
    int cr = cc6[k] + 8 * pp6[k];
    if (cr >= 96) cr -= 96;
    if (cr >= 96) cr -= 96;
#pragma unroll
    for (int u = 0; u < 8; ++u) Xa[(pp6[k] * 8 + u) * 104 + cr] = xv6[k][u];
  }
  __syncthreads();

  bf16x8 af[24];
  int rotb = n16 >> 3;
#pragma unroll
  for (int mi = 0; mi < 8; ++mi)
#pragma unroll
    for (int k = 0; k < 3; ++k) {
      int gidx = k * 4 + quad + 2 * mi + rotb;
      if (gidx >= 24) gidx -= 24; else if (gidx >= 12) gidx -= 12;
      af[mi * 3 + k] = ld8(&Xa[(mi * 16 + n16) * 104 + gidx * 8]);
    }
  __syncthreads();   // Xa dead; Ha overlays

  int ph = w & 1, fh = w >> 1;
  f32x4 acc2[4][3];
#pragma unroll
  for (int g2 = 0; g2 < 4; ++g2)
#pragma unroll
    for (int ni = 0; ni < 3; ++ni) { f32x4 z = {0.f, 0.f, 0.f, 0.f}; acc2[g2][ni] = z; }

#pragma unroll
  for (int half = 0; half < 2; ++half) {
    // GEMM1: wave's 48 features x 128 px; weight frag reused over 8 mi (1:8)
#pragma unroll
    for (int ni = 0; ni < 3; ++ni) {
      f32x4 acc[8];
#pragma unroll
      for (int mi = 0; mi < 8; ++mi) { f32x4 z = {0.f, 0.f, 0.f, 0.f}; acc[mi] = z; }
#pragma unroll
      for (int kk = 0; kk < 3; ++kk) {
        bf16x8 bf = wf[(half * 3 + ni) * 3 + kk];
#pragma unroll
        for (int mi = 0; mi < 8; ++mi)
          acc[mi] = __builtin_amdgcn_mfma_f32_16x16x32_bf16(af[mi * 3 + kk], bf, acc[mi], 0, 0, 0);
      }
      int fl = w * 48 + ni * 16 + n16;
      float b1v = b1v6[half * 3 + ni];
#pragma unroll
      for (int mi = 0; mi < 8; ++mi)
#pragma unroll
        for (int r = 0; r < 4; ++r)
          Ha[(mi * 16 + quad * 4 + r) * 200 + fl] = f2bf(gelu_sig(acc[mi][r] + b1v));
    }
    __syncthreads();

    // GEMM2: wave = (ph px-half: 4 groups of 16 px, fh feat-half: 48 out-features);
    // w2 frags prefetched in batches of 9, each reused over 4 px-groups (1:4)
#pragma unroll
    for (int kc = 0; kc < 2; ++kc) {
      bf16x8 w2f[9];
#pragma unroll
      for (int kk = 0; kk < 3; ++kk)
#pragma unroll
        for (int ni = 0; ni < 3; ++ni)
          w2f[kk * 3 + ni] = ld8(&w2b[((size_t)(fh * 48 + ni * 16 + n16)) * 384 +
                                      half * 192 + (kc * 3 + kk) * 32 + quad * 8]);
#pragma unroll
      for (int kk = 0; kk < 3; ++kk) {
        int k0 = kc * 3 + kk;
        bf16x8 a2[4];
#pragma unroll
        for (int g2 = 0; g2 < 4; ++g2)
          a2[g2] = ld8(&Ha[((ph * 4 + g2) * 16 + n16) * 200 + k0 * 32 + quad * 8]);
#pragma unroll
        for (int ni = 0; ni < 3; ++ni)
#pragma unroll
          for (int g2 = 0; g2 < 4; ++g2)
            acc2[g2][ni] = __builtin_amdgcn_mfma_f32_16x16x32_bf16(a2[g2], w2f[kk * 3 + ni], acc2[g2][ni], 0, 0, 0);
      }
    }
    __syncthreads();   // Ha(half) consumed; safe for next half's GEMM1 writes / Ot overlay
  }

  // Ot overlay (Ha dead)
#pragma unroll
  for (int g2 = 0; g2 < 4; ++g2)
#pragma unroll
    for (int ni = 0; ni < 3; ++ni)
#pragma unroll
      for (int r = 0; r < 4; ++r)
        Ot[(fh * 48 + ni * 16 + n16) * 132 + (ph * 4 + g2) * 16 + quad * 4 + r] = acc2[g2][ni][r];
  __syncthreads();

#pragma unroll
  for (int k = 0; k < 12; ++k) {
    int i = t + k * 256;
    int o = i >> 5, pg = i & 31;
    size_t gbase = ((size_t)b * CHN + o) * HW + rr0 + pg * 4;
    ushort4 xv = *(const ushort4*)&x[gbase];
    float4 ov = *(const float4*)&Ot[o * 132 + pg * 4];
    float bb = b2[o];
    float4 res;
    res.x = bf2f(xv.x) + ov.x + bb;
    res.y = bf2f(xv.y) + ov.y + bb;
    res.z = bf2f(xv.z) + ov.z + bb;
    res.w = bf2f(xv.w) + ov.w + bb;
    *(float4*)&op[gbase] = res;
  }
}

extern "C" void kernel_launch(void* const* d_in, const int* in_sizes, int n_in,
                              void* d_out, int out_size, void* d_ws, size_t ws_size,
                              hipStream_t stream) {
  (void)in_sizes; (void)n_in; (void)out_size; (void)ws_size;
  const float* low   = (const float*)d_in[0];
  const float* high  = (const float*)d_in[1];
  const float* ln1_g = (const float*)d_in[2];
  const float* ln1_b = (const float*)d_in[3];
  const float* ln2_g = (const float*)d_in[4];
  const float* ln2_b = (const float*)d_in[5];
  const float* se_w1 = (const float*)d_in[6];
  const float* se_w2 = (const float*)d_in[7];
  const float* wq_l  = (const float*)d_in[8];
  const float* wk_h  = (const float*)d_in[9];
  const float* wv_h  = (const float*)d_in[10];
  const float* wq_h  = (const float*)d_in[11];
  const float* wk_l  = (const float*)d_in[12];
  const float* wv_l  = (const float*)d_in[13];
  const float* wp_l  = (const float*)d_in[14];
  const float* wp_h  = (const float*)d_in[15];
  const float* mw1   = (const float*)d_in[16];
  const float* mb1   = (const float*)d_in[17];
  const float* mw2   = (const float*)d_in[18];
  const float* mb2   = (const float*)d_in[19];

  // ws layout, ~98.4 MB total (poison-fill WRITE_SIZE shows ws = 256 MiB)
  float* ws = (float*)d_ws;
  unsigned short* w1b = (unsigned short*)ws;
  unsigned short* w2b = w1b + 36864;
  unsigned short* wqb = w2b + 36864;
  unsigned short* wpb = wqb + 55296;                  // front total 147456 shorts = 73728 floats
  float* mu_l  = ws + 73728;
  float* rs_l  = mu_l + 32768;
  float* mu_h  = rs_l + 32768;
  float* rs_h  = mu_h + 32768;
  float* poolb = rs_h + 32768;
  float* s_se  = poolb + 256;
  unsigned short* low1b  = (unsigned short*)(s_se + 256);
  unsigned short* high1b = low1b + 3145728;
  unsigned short* qkv    = high1b + 3145728;          // 18874368 shorts
  unsigned short* Owin   = qkv + 18874368;            // 23617536 shorts (2 dirs x 2 b)

  cvt_k<<<216, 256, 0, stream>>>(mw1, mw2, wq_l, wk_h, wv_h, wq_h, wk_l, wv_l,
                                 wp_l, wp_h, w1b, w2b, wqb, wpb);

  ln2_k<float><<<64, 256, 0, stream>>>(low, high, mu_l, rs_l, mu_h, rs_h);

  for (int pass = 0; pass < 2; ++pass) {
    const float* g  = pass ? ln2_g : ln1_g;
    const float* bt = pass ? ln2_b : ln1_b;
    int shift = pass ? 4 : 0;

    if (pass == 0) {
      pool_k<float><<<192, 256, 0, stream>>>(high, mu_h, rs_h, g, bt, poolb);
      se_k<<<1, 256, 0, stream>>>(poolb, se_w1, se_w2, s_se);
      proj_k<float><<<512, 256, 0, stream>>>(low, high, mu_l, rs_l, mu_h, rs_h,
                                             g, bt, s_se, wqb, qkv);
      attn_k<<<2 * 1922, 256, 0, stream>>>(qkv, Owin, shift);
      combine_k<float><<<1024, 256, 0, stream>>>(low, high, low1b, high1b, Owin,
                                                 mu_l, rs_l, mu_h, rs_h,
                                                 g, bt, wpb, shift);
    } else {
      pool_k<unsigned short><<<192, 256, 0, stream>>>(high1b, mu_h, rs_h, g, bt, poolb);
      se_k<<<1, 256, 0, stream>>>(poolb, se_w1, se_w2, s_se);
      proj_k<unsigned short><<<512, 256, 0, stream>>>(low1b, high1b, mu_l, rs_l, mu_h, rs_h,
                                                      g, bt, s_se, wqb, qkv);
      attn_k<<<2 * 1922, 256, 0, stream>>>(qkv, Owin, shift);
      combine_k<unsigned short><<<1024, 256, 0, stream>>>(low1b, high1b, low1b, high1b, Owin,
                                                          mu_l, rs_l, mu_h, rs_h,
                                                          g, bt, wpb, shift);
    }
  }
  mlp_k<<<512, 256, 0, stream>>>(low1b, high1b, (float*)d_out, w1b, mb1, w2b, mb2);
}

// Round 12
// 318.238 us; speedup vs baseline: 1.4765x; 1.0193x over previous
//
#include <hip/hip_runtime.h>
#include <math.h>

#define CHN 96
#define HW 16384
#define NWIN 31
#define SCALE_F 0.20412414523193154f
#define SCALE_L2 0.294488893f   // SCALE_F * log2(e): exp(s*SCALE) == exp2(s*SCALE_L2)

typedef __attribute__((ext_vector_type(8))) __bf16 bf16x8;
typedef __attribute__((ext_vector_type(4))) float f32x4;
typedef __attribute__((ext_vector_type(8))) unsigned short u16x8;

__device__ __forceinline__ int rfl(int v) { return __builtin_amdgcn_readfirstlane(v); }

__device__ __forceinline__ unsigned short f2bf(float f) {
  union { float f; unsigned u; } v; v.f = f;
  unsigned r = v.u + 0x7fffu + ((v.u >> 16) & 1u);
  return (unsigned short)(r >> 16);
}
__device__ __forceinline__ float bf2f(unsigned short h) {
  union { unsigned u; float f; } v; v.u = ((unsigned)h) << 16;
  return v.f;
}
__device__ __forceinline__ float fexp2(float x) {
#if __has_builtin(__builtin_amdgcn_exp2f)
  return __builtin_amdgcn_exp2f(x);
#else
  return __expf(x * 0.6931471806f);
#endif
}
__device__ __forceinline__ float ldv(const float* p, size_t i) { return p[i]; }
__device__ __forceinline__ float ldv(const unsigned short* p, size_t i) { return bf2f(p[i]); }
__device__ __forceinline__ bf16x8 ld8(const unsigned short* p) {
  return *(const bf16x8*)__builtin_assume_aligned(p, 16);
}
__device__ __forceinline__ u16x8 ld8u(const unsigned short* p) {
  return *(const u16x8*)__builtin_assume_aligned(p, 16);
}
__device__ __forceinline__ bf16x8 zf8() {
  union { unsigned long long u[2]; bf16x8 v; } z;
  z.u[0] = 0ull; z.u[1] = 0ull;
  return z.v;
}
__device__ __forceinline__ bf16x8 onesf8() {
  union { unsigned short s[8]; bf16x8 v; } o;
#pragma unroll
  for (int i = 0; i < 8; ++i) o.s[i] = 0x3F80;  // bf16 1.0
  return o.v;
}
// vector load helpers: 8 / 4 floats from fp32 or bf16 source
__device__ __forceinline__ void ld8f(const float* p, float* o) {
  float4 a = *(const float4*)__builtin_assume_aligned(p, 16);
  float4 b = *(const float4*)__builtin_assume_aligned(p + 4, 16);
  o[0] = a.x; o[1] = a.y; o[2] = a.z; o[3] = a.w;
  o[4] = b.x; o[5] = b.y; o[6] = b.z; o[7] = b.w;
}
__device__ __forceinline__ void ld8f(const unsigned short* p, float* o) {
  u16x8 v = ld8u(p);
#pragma unroll
  for (int u = 0; u < 8; ++u) o[u] = bf2f(v[u]);
}
__device__ __forceinline__ void ld4f(const float* p, float* o) {
  float4 a = *(const float4*)__builtin_assume_aligned(p, 16);
  o[0] = a.x; o[1] = a.y; o[2] = a.z; o[3] = a.w;
}
__device__ __forceinline__ void ld4f(const unsigned short* p, float* o) {
  ushort4 v = *(const ushort4*)__builtin_assume_aligned(p, 8);
  o[0] = bf2f(v.x); o[1] = bf2f(v.y); o[2] = bf2f(v.z); o[3] = bf2f(v.w);
}

// GELU via x*sigmoid(1.702x); |err vs exact| <= ~0.02 (within absmax budget)
__device__ __forceinline__ float gelu_sig(float x) {
  return x * __builtin_amdgcn_rcpf(1.f + __expf(-1.702f * x));
}

// ---------------- LN stats (pass 0 only), 1 px/thread, grid 256 ----------------
// R12: was grid 64 (0.25 blocks/CU, chip 75% idle on a 25 MB read). 1 px/thread at
// 256 blocks; per-c loads are 64 consecutive px per wave -> fully coalesced.
template <typename T>
__global__ __launch_bounds__(256) void ln2_k(const T* __restrict__ xl, const T* __restrict__ xh,
                                             float* __restrict__ mu_l, float* __restrict__ rs_l,
                                             float* __restrict__ mu_h, float* __restrict__ rs_h) {
  int which = blockIdx.x >> 7;           // 128 blocks per tensor
  int idx = (blockIdx.x & 127) * 256 + threadIdx.x;   // 0..32767 (2 batches x 16384 px)
  const T* xt = which ? xh : xl;
  float* mu = which ? mu_h : mu_l;
  float* rstd = which ? rs_h : rs_l;
  int b = idx >> 14, p = idx & 16383;
  const T* xp = xt + (size_t)b * CHN * HW + p;
  float s = 0.f, s2 = 0.f;
#pragma unroll 8
  for (int c = 0; c < CHN; ++c) {
    float v = ldv(xp, (size_t)c * HW);
    s += v;
    s2 = fmaf(v, v, s2);
  }
  float m = s * (1.f / 96.f);
  mu[idx] = m;
  rstd[idx] = rsqrtf(fmaf(-m, m, s2 * (1.f / 96.f)) + 1e-5f);
}

// ---------------- SE pool: partial sums, grid 768 = 2 b x 96 c x 4 px-chunks ----------------
// R12: was grid 192 (0.75 blocks/CU). Each block reduces a 4096-px chunk of one
// (b,c); writes poolp[chunk*192 + b*96+c]. g/bt application moved to se_k.
template <typename T>
__global__ __launch_bounds__(256) void pool_k(const T* __restrict__ x,
                                              const float* __restrict__ mu,
                                              const float* __restrict__ rstd,
                                              float* __restrict__ poolp) {
  int blk = blockIdx.x;
  int chunk = blk & 3, bc = blk >> 2;    // bc in 0..191
  int b = bc / CHN, c = bc - b * CHN;
  const T* xp = x + (size_t)(b * CHN + c) * HW;
  const float* mup = mu + b * HW;
  const float* rp = rstd + b * HW;
  int t = threadIdx.x;
  float s = 0.f;
  int base = chunk * 4096;
#pragma unroll
  for (int it = 0; it < 4; ++it) {
    int p0 = base + it * 1024 + t * 4;
    float v4[4];
    ld4f(xp + p0, v4);
    float4 m4 = *(const float4*)&mup[p0];
    float4 r4 = *(const float4*)&rp[p0];
    s += (v4[0] - m4.x) * r4.x + (v4[1] - m4.y) * r4.y +
         (v4[2] - m4.z) * r4.z + (v4[3] - m4.w) * r4.w;
  }
  __shared__ float red[256];
  red[t] = s;
  __syncthreads();
  for (int k = 128; k > 0; k >>= 1) {
    if (t < k) red[t] += red[t + k];
    __syncthreads();
  }
  if (t == 0) poolp[chunk * 192 + bc] = red[0];
}

// ---------------- SE gate (sums 4 pool partials, applies g/bt) ----------------
__global__ __launch_bounds__(256) void se_k(const float* __restrict__ poolp,
                                            const float* __restrict__ g,
                                            const float* __restrict__ bt,
                                            const float* __restrict__ w1,
                                            const float* __restrict__ w2,
                                            float* __restrict__ s_se) {
  __shared__ float pl[192];
  int t = threadIdx.x;
  if (t < 192) {
    int c = t % CHN;
    float raw = poolp[t] + poolp[192 + t] + poolp[384 + t] + poolp[576 + t];
    pl[t] = g[c] * (raw * (1.f / 16384.f)) + bt[c];
  }
  __syncthreads();
  if (t >= 2 * CHN) return;
  int b = t / CHN, c = t % CHN;
  int i = c >> 5, cl = c & 31;
  const float* pg = &pl[b * CHN + i * 32];
  const float* w1p = w1 + i * 64;
  float z0 = 0.f, z1 = 0.f;
#pragma unroll 8
  for (int k = 0; k < 32; ++k) {
    float p = pg[k];
    z0 = fmaf(p, w1p[k], z0);
    z1 = fmaf(p, w1p[32 + k], z1);
  }
  z0 = fmaxf(z0, 0.f);
  z1 = fmaxf(z1, 0.f);
  float a = z0 * w2[i * 64 + cl * 2] + z1 * w2[i * 64 + cl * 2 + 1];
  s_se[t] = 1.f / (1.f + __expf(-a));
}

// ---------------- weight convert fp32 -> bf16 ----------------
__global__ __launch_bounds__(256) void cvt_k(const float* __restrict__ w1,
                                             const float* __restrict__ w2,
                                             const float* __restrict__ p0,
                                             const float* __restrict__ p1,
                                             const float* __restrict__ p2,
                                             const float* __restrict__ p3,
                                             const float* __restrict__ p4,
                                             const float* __restrict__ p5,
                                             const float* __restrict__ q0,
                                             const float* __restrict__ q1,
                                             unsigned short* __restrict__ w1b,
                                             unsigned short* __restrict__ w2b,
                                             unsigned short* __restrict__ wqb,
                                             unsigned short* __restrict__ wpb) {
  int i = blockIdx.x * 256 + threadIdx.x;
  if (i < 36864) {
    w1b[i] = f2bf(w1[i]);
    w2b[i] = f2bf(w2[i]);
  }
  if (i < 55296) {
    int tt = i / 9216, rem = i - tt * 9216;
    const float* ps[6] = {p0, p1, p2, p3, p4, p5};
    wqb[i] = f2bf(ps[tt][rem]);
  }
  if (i < 18432) {
    wpb[i] = f2bf(i < 9216 ? q0[i] : q1[i - 9216]);
  }
}

// ---------------- MFMA full-image QKV projection ----------------
// qkv slots [t][b]; Q/K (t=0,1,3,4) pixel-major [pix][96]; V (t=2,5) channel-major [c][HW].
// Staging: thread owns (channel, fixed 8-px group) -> 8-px vector loads, stats hoisted.
// LDS staging uses group-rotation swizzle: col' = (c + 8*(row>>3)) mod 96 so the
// pixel-major scatter writes spread over all 8 16B-slots mod 128 (was 16-way conflict).
template <typename T>
__global__ __launch_bounds__(256, 3) void proj_k(
    const T* __restrict__ lowp, const T* __restrict__ highp,
    const float* __restrict__ mu_l, const float* __restrict__ rs_l,
    const float* __restrict__ mu_h, const float* __restrict__ rs_h,
    const float* __restrict__ g, const float* __restrict__ bt,
    const float* __restrict__ s_se,
    const unsigned short* __restrict__ wqb,
    unsigned short* __restrict__ qkv) {
  __shared__ __align__(16) unsigned short sh[13312];  // Xl[64*104] | Xh[64*104]; later tb[4][32*104]
  unsigned short* Xl = sh;
  unsigned short* Xh = sh + 6656;
  int t = threadIdx.x;
  int lane = t & 63;
  int w = rfl(t >> 6);
  int n16 = lane & 15, quad = lane >> 4;
  int tile = blockIdx.x;
  int Pb = tile * 64;
  int b = Pb >> 14, rr0 = Pb & 16383;

  // ---- stage: thread's fixed 8 pixels = rr0 + (t&7)*8 .. +7 ----
  {
    int pg = t & 7;
    float mul8[8], rsl8[8], muh8[8], rsh8[8];
    ld8f(mu_l + (size_t)b * HW + rr0 + pg * 8, mul8);
    ld8f(rs_l + (size_t)b * HW + rr0 + pg * 8, rsl8);
    ld8f(mu_h + (size_t)b * HW + rr0 + pg * 8, muh8);
    ld8f(rs_h + (size_t)b * HW + rr0 + pg * 8, rsh8);
#pragma unroll
    for (int k = 0; k < 3; ++k) {
      int c = (t + k * 256) >> 3;
      float gc = g[c], bc = bt[c], sc = s_se[b * CHN + c];
      float xl8[8], xh8[8];
      ld8f(lowp + (size_t)(b * CHN + c) * HW + rr0 + pg * 8, xl8);
      ld8f(highp + (size_t)(b * CHN + c) * HW + rr0 + pg * 8, xh8);
      int cr = c + pg * 8; if (cr >= 96) cr -= 96;   // rotated col (row>>3 == pg)
#pragma unroll
      for (int u = 0; u < 8; ++u) {
        int px = pg * 8 + u;
        Xl[px * 104 + cr] = f2bf((xl8[u] - mul8[u]) * rsl8[u] * gc + bc);
        Xh[px * 104 + cr] = f2bf(((xh8[u] - muh8[u]) * rsh8[u] * gc + bc) * sc);
      }
    }
  }
  __syncthreads();

  // register-cache A-frags for BOTH the main (pixel-major) tensor and the V tensor
  int tmain = (0x4310 >> (4 * w)) & 15;          // w: 0->t0, 1->t1, 2->t3, 3->t4
  const unsigned short* Xm = (w == 0 || w == 3) ? Xl : Xh;
  const unsigned short* Xv = (w < 2) ? Xh : Xl;
  bf16x8 af[12], av[12];
  int rotb = n16 >> 3;
#pragma unroll
  for (int mi = 0; mi < 4; ++mi)
#pragma unroll
    for (int k = 0; k < 3; ++k) {
      int gidx = k * 4 + quad + 2 * mi + rotb; if (gidx >= 12) gidx -= 12;
      af[mi * 3 + k] = ld8(&Xm[(mi * 16 + n16) * 104 + gidx * 8]);
      av[mi * 3 + k] = ld8(&Xv[(mi * 16 + n16) * 104 + gidx * 8]);
    }
  __syncthreads();   // X dead; tb overlays

  unsigned short* tw = sh + w * 3328;
#pragma unroll
  for (int half = 0; half < 2; ++half) {
#pragma unroll
    for (int ni = 0; ni < 6; ++ni) {
      f32x4 a0 = {0.f, 0.f, 0.f, 0.f}, a1 = {0.f, 0.f, 0.f, 0.f};
#pragma unroll
      for (int k = 0; k < 3; ++k) {
        bf16x8 bf = ld8(&wqb[((size_t)tmain * 96 + ni * 16 + n16) * 96 + k * 32 + quad * 8]);
        a0 = __builtin_amdgcn_mfma_f32_16x16x32_bf16(af[(half * 2 + 0) * 3 + k], bf, a0, 0, 0, 0);
        a1 = __builtin_amdgcn_mfma_f32_16x16x32_bf16(af[(half * 2 + 1) * 3 + k], bf, a1, 0, 0, 0);
      }
#pragma unroll
      for (int r = 0; r < 4; ++r) {
        tw[(quad * 4 + r) * 104 + ni * 16 + n16] = f2bf(a0[r]);
        tw[(16 + quad * 4 + r) * 104 + ni * 16 + n16] = f2bf(a1[r]);
      }
    }
    // wave-local readout (per-wave DS ops in-order; no barrier)
#pragma unroll
    for (int c6 = 0; c6 < 6; ++c6) {
      int chunk = lane + 64 * c6;
      int pl2 = chunk / 12, kb2 = chunk - pl2 * 12;
      u16x8 v = ld8u(&tw[pl2 * 104 + kb2 * 8]);
      size_t pix = (size_t)rr0 + half * 32 + pl2;
      *(u16x8*)&qkv[((size_t)(tmain * 2 + b) * HW + pix) * 96 + kb2 * 8] = v;
    }
  }

  // V units from register-cached av
  int tv = (w < 2) ? 2 : 5;
  int nbase = (w & 1) * 3;
#pragma unroll
  for (int jj = 0; jj < 3; ++jj) {
    int ni = nbase + jj;
    f32x4 acc[4];
#pragma unroll
    for (int mi = 0; mi < 4; ++mi) { f32x4 z = {0.f, 0.f, 0.f, 0.f}; acc[mi] = z; }
#pragma unroll
    for (int k = 0; k < 3; ++k) {
      bf16x8 bf = ld8(&wqb[((size_t)tv * 96 + ni * 16 + n16) * 96 + k * 32 + quad * 8]);
#pragma unroll
      for (int mi = 0; mi < 4; ++mi)
        acc[mi] = __builtin_amdgcn_mfma_f32_16x16x32_bf16(av[mi * 3 + k], bf, acc[mi], 0, 0, 0);
    }
    int feat = ni * 16 + n16;
    size_t rowbase = ((size_t)(tv * 2 + b) * CHN + feat) * HW + rr0;
#pragma unroll
    for (int mi = 0; mi < 4; ++mi) {
      ushort4 o4;
      o4.x = f2bf(acc[mi][0]);
      o4.y = f2bf(acc[mi][1]);
      o4.z = f2bf(acc[mi][2]);
      o4.w = f2bf(acc[mi][3]);
      *(ushort4*)&qkv[rowbase + mi * 16 + quad * 4] = o4;
    }
  }
}

// ---------------- MFMA window attention (both dirs fused in one launch) ----------------
// grid = 2 dirs x 2 batches x 961 windows = 3844 blocks. Owin slot (dir*2 + b).
// XCD swizzle: 3844 % 8 = 4 -> bijective chunked variant (q=480, r=4):
//   chunk start = x<4 ? x*481 : 1924 + (x-4)*480   (x = bid0 & 7, y = bid0 >> 3)
// [R7 ERRATA: naive remap at nwg=3844 skipped half the windows; absmax was the tell.]
// [R9 ERRATA: direct per-lane V loads from channel-major global = 8B gather with
//  lanes 32KB apart -> FETCH 155MB + 334MB write amplification, 2.7x slower. V MUST
//  be staged cooperatively through LDS; coalescing is a cross-lane property.]
// T14 staging: issue all 6 V-loads + 8 Q/K-loads before any ds_write.
// Softmax normalization via extra MFMA against ones-frag; no-max softmax.
__global__ __launch_bounds__(256, 5) void attn_k(
    const unsigned short* __restrict__ qkv,
    unsigned short* __restrict__ Owin, int shift) {
  __shared__ __align__(16) unsigned short shb[16128];  // Vs[96*72]=6912 | P32[4*64*36]=9216
  unsigned short* Vs = shb;                            // later overlaid by Os[64*104]
  unsigned short* P32 = shb + 6912;
  unsigned short* Os = shb;

  int bid0 = blockIdx.x;
  int x8 = bid0 & 7, y8 = bid0 >> 3;
  int bid = (x8 < 4 ? x8 * 481 : 1924 + (x8 - 4) * 480) + y8;  // bijective on [0,3844)
  int dir = bid / 1922;
  int rem = bid - dir * 1922;
  int b = rem / 961;
  int win = rem - b * 961;
  int wy = win / NWIN, wx = win % NWIN;
  int t = threadIdx.x;
  int lane = t & 63;
  int h = rfl(t >> 6);
  int n16 = lane & 15, quad = lane >> 4;

  // ---- T14: issue ALL global loads (V x6, Q x4, K x4) before any LDS write ----
  ushort4 vv[6];
  int vdst[6];
  {
    const unsigned short* vbase = qkv + (size_t)((dir * 3 + 2) * 2 + b) * CHN * HW;
#pragma unroll
    for (int k = 0; k < 6; ++k) {
      int i = t + k * 256;
      int c = i >> 4, ry = (i >> 1) & 7, hx = i & 1;
      int gy = (wy * 4 + ry + shift) & 127;
      int gx = (wx * 4 + hx * 4 + shift) & 127;
      vv[k] = *(const ushort4*)(vbase + (size_t)c * HW + gy * 128 + gx);
      vdst[k] = c * 72 + ry * 8 + hx * 4;
    }
  }

  bf16x8 qa[4], kb4[4];
  {
    const unsigned short* qpm = qkv + (size_t)((dir * 3 + 0) * 2 + b) * CHN * HW;
    const unsigned short* kpm = qkv + (size_t)((dir * 3 + 1) * 2 + b) * CHN * HW;
    if (quad < 3) {
#pragma unroll
      for (int ni = 0; ni < 4; ++ni) {
        int n = ni * 16 + n16;
        int gy = (wy * 4 + (n >> 3) + shift) & 127;
        int gx = (wx * 4 + (n & 7) + shift) & 127;
        size_t pix = (size_t)gy * 128 + gx;
        qa[ni] = ld8(&qpm[pix * 96 + h * 24 + quad * 8]);
        kb4[ni] = ld8(&kpm[pix * 96 + h * 24 + quad * 8]);
      }
    } else {
#pragma unroll
      for (int ni = 0; ni < 4; ++ni) { qa[ni] = zf8(); kb4[ni] = zf8(); }
    }
  }

  // commit V to LDS (loads above already in flight)
#pragma unroll
  for (int k = 0; k < 6; ++k) *(ushort4*)&Vs[vdst[k]] = vv[k];
  __syncthreads();

  const int hP = h * (64 * 36);

  f32x4 sa[4][4];
#pragma unroll
  for (int ni = 0; ni < 4; ++ni)
#pragma unroll
    for (int mi = 0; mi < 4; ++mi) {
      f32x4 z = {0.f, 0.f, 0.f, 0.f};
      sa[ni][mi] = __builtin_amdgcn_mfma_f32_16x16x32_bf16(qa[ni], kb4[mi], z, 0, 0, 0);
    }

  // unnormalized exponentials (no-max softmax; scores bounded)
#pragma unroll
  for (int ni = 0; ni < 4; ++ni)
#pragma unroll
    for (int mi = 0; mi < 4; ++mi)
#pragma unroll
      for (int r = 0; r < 4; ++r)
        sa[ni][mi][r] = fexp2(sa[ni][mi][r] * SCALE_L2);

  const bf16x8 ones = onesf8();
  f32x4 oa[4][2];
  f32x4 sacc[4];
#pragma unroll
  for (int ni = 0; ni < 4; ++ni) {
    f32x4 z = {0.f, 0.f, 0.f, 0.f};
    oa[ni][0] = z; oa[ni][1] = z; sacc[ni] = z;
  }
#pragma unroll
  for (int s = 0; s < 2; ++s) {
#pragma unroll
    for (int ni = 0; ni < 4; ++ni)
#pragma unroll
      for (int r = 0; r < 4; ++r) {
#pragma unroll
        for (int mm = 0; mm < 2; ++mm) {
          int mi = s * 2 + mm;
          P32[hP + (ni * 16 + quad * 4 + r) * 36 + mm * 16 + n16] = f2bf(sa[ni][mi][r]);
        }
      }
    bf16x8 pa[4];
#pragma unroll
    for (int ni = 0; ni < 4; ++ni) pa[ni] = ld8(&P32[hP + (ni * 16 + n16) * 36 + quad * 8]);
    bf16x8 vb0 = ld8(&Vs[(h * 24 + n16) * 72 + s * 32 + quad * 8]);
    bf16x8 vb1 = (n16 < 8) ? ld8(&Vs[(h * 24 + 16 + n16) * 72 + s * 32 + quad * 8]) : zf8();
#pragma unroll
    for (int ni = 0; ni < 4; ++ni) {
      oa[ni][0] = __builtin_amdgcn_mfma_f32_16x16x32_bf16(pa[ni], vb0, oa[ni][0], 0, 0, 0);
      oa[ni][1] = __builtin_amdgcn_mfma_f32_16x16x32_bf16(pa[ni], vb1, oa[ni][1], 0, 0, 0);
      sacc[ni] = __builtin_amdgcn_mfma_f32_16x16x32_bf16(pa[ni], ones, sacc[ni], 0, 0, 0);
    }
  }

  // normalize O by MFMA-computed row sums (same accumulator layout: row = quad*4+r)
#pragma unroll
  for (int ni = 0; ni < 4; ++ni)
#pragma unroll
    for (int r = 0; r < 4; ++r) {
      float inv = __builtin_amdgcn_rcpf(sacc[ni][r]);
      oa[ni][0][r] *= inv;
      oa[ni][1][r] *= inv;
    }
  __syncthreads();   // Vs dead; Os overlays

  // stage O -> Os[px][96] (pad 104), then coalesced 16B stores
#pragma unroll
  for (int ni = 0; ni < 4; ++ni)
#pragma unroll
    for (int r = 0; r < 4; ++r) {
      int n = ni * 16 + quad * 4 + r;
      Os[n * 104 + h * 24 + n16] = f2bf(oa[ni][0][r]);
      if (n16 < 8) Os[n * 104 + h * 24 + 16 + n16] = f2bf(oa[ni][1][r]);
    }
  __syncthreads();

  {
    unsigned short* obase = Owin + (size_t)((dir * 2 + b) * 961 + win) * 64 * CHN;
#pragma unroll
    for (int k = 0; k < 3; ++k) {
      int i = t + k * 256;               // 0..767
      int px = i / 12, cb = i - px * 12;
      u16x8 v = ld8u(&Os[px * 104 + cb * 8]);
      *(u16x8*)&obase[px * CHN + cb * 8] = v;
    }
  }
}

// ---------------- MFMA combine + fused next-pass LN stats (low+high fused) ----------------
// grid 1024; XCD-chunk swizzle (1024 = 8*128, divisible -> simple form is bijective).
// sel picks (low, dir0) vs (high, dir1) stream.
template <typename T>
__global__ __launch_bounds__(256) void combine_k(
    const T* __restrict__ base_l, const T* __restrict__ base_h,
    unsigned short* __restrict__ out_l, unsigned short* __restrict__ out_h,
    const unsigned short* __restrict__ Owin,
    float* __restrict__ mu_lp, float* __restrict__ rs_lp,
    float* __restrict__ mu_hp, float* __restrict__ rs_hp,
    const float* __restrict__ g, const float* __restrict__ bt,
    const unsigned short* __restrict__ wpb2, int shift) {
  __shared__ __align__(16) unsigned short sb[96 * 72];   // at [64][104] then ot [96][72]
  __shared__ float red[2][4][64];
  unsigned short* at = sb;
  unsigned short* ot = sb;
  int t = threadIdx.x;
  int lane = t & 63;
  int w = rfl(t >> 6);
  int n16 = lane & 15, quad = lane >> 4;
  int wg = (blockIdx.x & 7) * 128 + (blockIdx.x >> 3);   // bijective XCD-chunk swizzle
  int sel = wg >> 9;
  int tile = wg & 511;                   // 0..511
  const T* base = sel ? base_h : base_l;
  unsigned short* outp = sel ? out_h : out_l;
  float* mu = sel ? mu_hp : mu_lp;
  float* rstd = sel ? rs_hp : rs_lp;
  const unsigned short* wpb = wpb2 + sel * 9216;

#pragma unroll
  for (int k = 0; k < 3; ++k) {
    int i = t + k * 256;
    int px = i / 12, cb = i - px * 12;
    int Ps = tile * 64 + px;
    int b = Ps >> 14, rem = Ps & 16383;
    int ys = rem >> 7, xs = rem & 127;
    int wyh = ys >> 2, wxh = xs >> 2;
    float acc[8];
#pragma unroll
    for (int u = 0; u < 8; ++u) acc[u] = 0.f;
    for (int dy = 0; dy < 2; ++dy) {
      int wyc = wyh - 1 + dy;
      if ((unsigned)wyc > 30u) continue;
      int py = ys - wyc * 4;
      for (int dx = 0; dx < 2; ++dx) {
        int wxc = wxh - 1 + dx;
        if ((unsigned)wxc > 30u) continue;
        int pxl = xs - wxc * 4;
        size_t o = ((size_t)((sel * 2 + b) * 961 + wyc * 31 + wxc) * 64 + py * 8 + pxl) * CHN + cb * 8;
        u16x8 v = ld8u(&Owin[o]);
#pragma unroll
        for (int u = 0; u < 8; ++u) acc[u] += bf2f(v[u]);
      }
    }
    union { u16x8 v; unsigned short s[8]; } pk;
#pragma unroll
    for (int u = 0; u < 8; ++u) pk.s[u] = f2bf(acc[u]);
    *(u16x8*)&at[px * 104 + cb * 8] = pk.v;
  }
  __syncthreads();

  bf16x8 af[3];
#pragma unroll
  for (int k = 0; k < 3; ++k)
    af[k] = ld8(&at[(w * 16 + n16) * 104 + k * 32 + quad * 8]);

  f32x4 acc6[6];
#pragma unroll
  for (int ni = 0; ni < 6; ++ni) {
    f32x4 z = {0.f, 0.f, 0.f, 0.f};
    acc6[ni] = z;
#pragma unroll
    for (int k = 0; k < 3; ++k) {
      bf16x8 bf = ld8(&wpb[(ni * 16 + n16) * 96 + k * 32 + quad * 8]);
      acc6[ni] = __builtin_amdgcn_mfma_f32_16x16x32_bf16(af[k], bf, acc6[ni], 0, 0, 0);
    }
  }
  __syncthreads();

#pragma unroll
  for (int ni = 0; ni < 6; ++ni)
#pragma unroll
    for (int r = 0; r < 4; ++r)
      ot[(ni * 16 + n16) * 72 + w * 16 + quad * 4 + r] = f2bf(acc6[ni][r]);
  __syncthreads();

  int Ps0 = tile * 64;
  int b = Ps0 >> 14, rem0 = Ps0 & 16383;
  int ys = rem0 >> 7, xs0 = rem0 & 127;
  int yt = (ys + shift) & 127;
  float icy = (ys >= 4 && ys <= 123) ? 0.5f : 1.f;
  int px = t & 63, c0w = t >> 6;
  int xs = xs0 + px;
  int xt = (xs + shift) & 127;
  float icx = (xs >= 4 && xs <= 123) ? 0.5f : 1.f;
  float invc = icy * icx;
  int pt = b * HW + yt * 128 + xt;
  float m = mu[pt], rs = rstd[pt];
  size_t pixoff = (size_t)yt * 128 + xt;
  float s = 0.f, sq = 0.f;
#pragma unroll
  for (int k = 0; k < 24; ++k) {
    int o = c0w + 4 * k;
    size_t gidx = ((size_t)b * CHN + o) * HW + pixoff;
    float bv = ldv(base, gidx);
    float lnv = (bv - m) * rs * g[o] + bt[o];
    float v = bv + lnv + bf2f(ot[o * 72 + px]) * invc;
    outp[gidx] = f2bf(v);
    s += v;
    sq = fmaf(v, v, sq);
  }
  red[0][c0w][px] = s;
  red[1][c0w][px] = sq;
  __syncthreads();
  if (t < 64) {
    int px2 = t;
    float ss = red[0][0][px2] + red[0][1][px2] + red[0][2][px2] + red[0][3][px2];
    float qq = red[1][0][px2] + red[1][1][px2] + red[1][2][px2] + red[1][3][px2];
    int xs2 = xs0 + px2;
    int xt2 = (xs2 + shift) & 127;
    int pt2 = b * HW + yt * 128 + xt2;
    float mm = ss * (1.f / 96.f);
    float var = fmaf(-mm, mm, qq * (1.f / 96.f));
    mu[pt2] = mm;
    rstd[pt2] = rsqrtf(var + 1e-5f);
  }
}

// ---------------- MFMA MLP ----------------
// 128-px tile, 4 waves, 512 blocks (2/CU). L2-load-latency bound: weight-frag
// reuse GEMM1 1:8, GEMM2 1:4; explicit prefetch arrays force deep MLP.
// NOTE: decode is built for a 512-block grid (sel = bid>>8, tile = bid&255).
// Launch with EXACTLY 512 blocks — 1024 made sel=2,3 write OOB past d_out (R4 crash).
__global__ __launch_bounds__(256, 2) void mlp_k(
    const unsigned short* __restrict__ x_l, const unsigned short* __restrict__ x_h,
    float* __restrict__ outp,
    const unsigned short* __restrict__ w1b, const float* __restrict__ b1,
    const unsigned short* __restrict__ w2b, const float* __restrict__ b2) {
  __shared__ __align__(16) unsigned char smem[51200];
  unsigned short* Xa = (unsigned short*)smem;   // [128][104] rotated groups
  unsigned short* Ha = (unsigned short*)smem;   // [128][200]
  float* Ot = (float*)smem;                     // [96][132]

  int t = threadIdx.x;
  int lane = t & 63;
  int w = rfl(t >> 6);
  int n16 = lane & 15, quad = lane >> 4;
  int sel = blockIdx.x >> 8;
  int tile = blockIdx.x & 255;
  const unsigned short* x = sel ? x_h : x_l;
  float* op = outp + (size_t)sel * (2 * CHN * HW);
  int Pb = tile * 128;
  int b = Pb >> 14, rr0 = Pb & 16383;

  // ---- stage: issue all 6 x-loads, then all 18 w1 frags + 6 biases (deep MLP),
  // then scatter x into Xa with group-rotation swizzle ----
  u16x8 xv6[6];
  int cc6[6], pp6[6];
#pragma unroll
  for (int k = 0; k < 6; ++k) {
    int i = t + k * 256;                 // 0..1535
    cc6[k] = i >> 4; pp6[k] = i & 15;    // 96 ch x 16 px-groups
    xv6[k] = ld8u(&x[((size_t)b * CHN + cc6[k]) * HW + rr0 + pp6[k] * 8]);
  }
  bf16x8 wf[18];
  float b1v6[6];
#pragma unroll
  for (int h2 = 0; h2 < 2; ++h2)
#pragma unroll
    for (int ni = 0; ni < 3; ++ni) {
      int nrow = h2 * 192 + w * 48 + ni * 16 + n16;
#pragma unroll
      for (int kk = 0; kk < 3; ++kk)
        wf[(h2 * 3 + ni) * 3 + kk] = ld8(&w1b[(size_t)nrow * 96 + kk * 32 + quad * 8]);
      b1v6[h2 * 3 + ni] = b1[nrow];
    }
#pragma unroll
  for (int k = 0; k < 6; ++k) {
    int cr = cc6[k] + 8 * pp6[k];
    if (cr >= 96) cr -= 96;
    if (cr >= 96) cr -= 96;
#pragma unroll
    for (int u = 0; u < 8; ++u) Xa[(pp6[k] * 8 + u) * 104 + cr] = xv6[k][u];
  }
  __syncthreads();

  bf16x8 af[24];
  int rotb = n16 >> 3;
#pragma unroll
  for (int mi = 0; mi < 8; ++mi)
#pragma unroll
    for (int k = 0; k < 3; ++k) {
      int gidx = k * 4 + quad + 2 * mi + rotb;
      if (gidx >= 24) gidx -= 24; else if (gidx >= 12) gidx -= 12;
      af[mi * 3 + k] = ld8(&Xa[(mi * 16 + n16) * 104 + gidx * 8]);
    }
  __syncthreads();   // Xa dead; Ha overlays

  int ph = w & 1, fh = w >> 1;
  f32x4 acc2[4][3];
#pragma unroll
  for (int g2 = 0; g2 < 4; ++g2)
#pragma unroll
    for (int ni = 0; ni < 3; ++ni) { f32x4 z = {0.f, 0.f, 0.f, 0.f}; acc2[g2][ni] = z; }

#pragma unroll
  for (int half = 0; half < 2; ++half) {
    // GEMM1: wave's 48 features x 128 px; weight frag reused over 8 mi (1:8)
#pragma unroll
    for (int ni = 0; ni < 3; ++ni) {
      f32x4 acc[8];
#pragma unroll
      for (int mi = 0; mi < 8; ++mi) { f32x4 z = {0.f, 0.f, 0.f, 0.f}; acc[mi] = z; }
#pragma unroll
      for (int kk = 0; kk < 3; ++kk) {
        bf16x8 bf = wf[(half * 3 + ni) * 3 + kk];
#pragma unroll
        for (int mi = 0; mi < 8; ++mi)
          acc[mi] = __builtin_amdgcn_mfma_f32_16x16x32_bf16(af[mi * 3 + kk], bf, acc[mi], 0, 0, 0);
      }
      int fl = w * 48 + ni * 16 + n16;
      float b1v = b1v6[half * 3 + ni];
#pragma unroll
      for (int mi = 0; mi < 8; ++mi)
#pragma unroll
        for (int r = 0; r < 4; ++r)
          Ha[(mi * 16 + quad * 4 + r) * 200 + fl] = f2bf(gelu_sig(acc[mi][r] + b1v));
    }
    __syncthreads();

    // GEMM2: wave = (ph px-half: 4 groups of 16 px, fh feat-half: 48 out-features);
    // w2 frags prefetched in batches of 9, each reused over 4 px-groups (1:4)
#pragma unroll
    for (int kc = 0; kc < 2; ++kc) {
      bf16x8 w2f[9];
#pragma unroll
      for (int kk = 0; kk < 3; ++kk)
#pragma unroll
        for (int ni = 0; ni < 3; ++ni)
          w2f[kk * 3 + ni] = ld8(&w2b[((size_t)(fh * 48 + ni * 16 + n16)) * 384 +
                                      half * 192 + (kc * 3 + kk) * 32 + quad * 8]);
#pragma unroll
      for (int kk = 0; kk < 3; ++kk) {
        int k0 = kc * 3 + kk;
        bf16x8 a2[4];
#pragma unroll
        for (int g2 = 0; g2 < 4; ++g2)
          a2[g2] = ld8(&Ha[((ph * 4 + g2) * 16 + n16) * 200 + k0 * 32 + quad * 8]);
#pragma unroll
        for (int ni = 0; ni < 3; ++ni)
#pragma unroll
          for (int g2 = 0; g2 < 4; ++g2)
            acc2[g2][ni] = __builtin_amdgcn_mfma_f32_16x16x32_bf16(a2[g2], w2f[kk * 3 + ni], acc2[g2][ni], 0, 0, 0);
      }
    }
    __syncthreads();   // Ha(half) consumed; safe for next half's GEMM1 writes / Ot overlay
  }

  // Ot overlay (Ha dead)
#pragma unroll
  for (int g2 = 0; g2 < 4; ++g2)
#pragma unroll
    for (int ni = 0; ni < 3; ++ni)
#pragma unroll
      for (int r = 0; r < 4; ++r)
        Ot[(fh * 48 + ni * 16 + n16) * 132 + (ph * 4 + g2) * 16 + quad * 4 + r] = acc2[g2][ni][r];
  __syncthreads();

#pragma unroll
  for (int k = 0; k < 12; ++k) {
    int i = t + k * 256;
    int o = i >> 5, pg = i & 31;
    size_t gbase = ((size_t)b * CHN + o) * HW + rr0 + pg * 4;
    ushort4 xv = *(const ushort4*)&x[gbase];
    float4 ov = *(const float4*)&Ot[o * 132 + pg * 4];
    float bb = b2[o];
    float4 res;
    res.x = bf2f(xv.x) + ov.x + bb;
    res.y = bf2f(xv.y) + ov.y + bb;
    res.z = bf2f(xv.z) + ov.z + bb;
    res.w = bf2f(xv.w) + ov.w + bb;
    *(float4*)&op[gbase] = res;
  }
}

extern "C" void kernel_launch(void* const* d_in, const int* in_sizes, int n_in,
                              void* d_out, int out_size, void* d_ws, size_t ws_size,
                              hipStream_t stream) {
  (void)in_sizes; (void)n_in; (void)out_size; (void)ws_size;
  const float* low   = (const float*)d_in[0];
  const float* high  = (const float*)d_in[1];
  const float* ln1_g = (const float*)d_in[2];
  const float* ln1_b = (const float*)d_in[3];
  const float* ln2_g = (const float*)d_in[4];
  const float* ln2_b = (const float*)d_in[5];
  const float* se_w1 = (const float*)d_in[6];
  const float* se_w2 = (const float*)d_in[7];
  const float* wq_l  = (const float*)d_in[8];
  const float* wk_h  = (const float*)d_in[9];
  const float* wv_h  = (const float*)d_in[10];
  const float* wq_h  = (const float*)d_in[11];
  const float* wk_l  = (const float*)d_in[12];
  const float* wv_l  = (const float*)d_in[13];
  const float* wp_l  = (const float*)d_in[14];
  const float* wp_h  = (const float*)d_in[15];
  const float* mw1   = (const float*)d_in[16];
  const float* mb1   = (const float*)d_in[17];
  const float* mw2   = (const float*)d_in[18];
  const float* mb2   = (const float*)d_in[19];

  // ws layout, ~98.4 MB total (poison-fill WRITE_SIZE shows ws = 256 MiB)
  float* ws = (float*)d_ws;
  unsigned short* w1b = (unsigned short*)ws;
  unsigned short* w2b = w1b + 36864;
  unsigned short* wqb = w2b + 36864;
  unsigned short* wpb = wqb + 55296;                  // front total 147456 shorts = 73728 floats
  float* mu_l  = ws + 73728;
  float* rs_l  = mu_l + 32768;
  float* mu_h  = rs_l + 32768;
  float* rs_h  = mu_h + 32768;
  float* poolb = rs_h + 32768;                        // 768 partials (4 chunks x 192)
  float* s_se  = poolb + 768;
  unsigned short* low1b  = (unsigned short*)(s_se + 256);
  unsigned short* high1b = low1b + 3145728;
  unsigned short* qkv    = high1b + 3145728;          // 18874368 shorts
  unsigned short* Owin   = qkv + 18874368;            // 23617536 shorts (2 dirs x 2 b)

  cvt_k<<<216, 256, 0, stream>>>(mw1, mw2, wq_l, wk_h, wv_h, wq_h, wk_l, wv_l,
                                 wp_l, wp_h, w1b, w2b, wqb, wpb);

  ln2_k<float><<<256, 256, 0, stream>>>(low, high, mu_l, rs_l, mu_h, rs_h);

  for (int pass = 0; pass < 2; ++pass) {
    const float* g  = pass ? ln2_g : ln1_g;
    const float* bt = pass ? ln2_b : ln1_b;
    int shift = pass ? 4 : 0;

    if (pass == 0) {
      pool_k<float><<<768, 256, 0, stream>>>(high, mu_h, rs_h, poolb);
      se_k<<<1, 256, 0, stream>>>(poolb, g, bt, se_w1, se_w2, s_se);
      proj_k<float><<<512, 256, 0, stream>>>(low, high, mu_l, rs_l, mu_h, rs_h,
                                             g, bt, s_se, wqb, qkv);
      attn_k<<<2 * 1922, 256, 0, stream>>>(qkv, Owin, shift);
      combine_k<float><<<1024, 256, 0, stream>>>(low, high, low1b, high1b, Owin,
                                                 mu_l, rs_l, mu_h, rs_h,
                                                 g, bt, wpb, shift);
    } else {
      pool_k<unsigned short><<<768, 256, 0, stream>>>(high1b, mu_h, rs_h, poolb);
      se_k<<<1, 256, 0, stream>>>(poolb, g, bt, se_w1, se_w2, s_se);
      proj_k<unsigned short><<<512, 256, 0, stream>>>(low1b, high1b, mu_l, rs_l, mu_h, rs_h,
                                                      g, bt, s_se, wqb, qkv);
      attn_k<<<2 * 1922, 256, 0, stream>>>(qkv, Owin, shift);
      combine_k<unsigned short><<<1024, 256, 0, stream>>>(low1b, high1b, low1b, high1b, Owin,
                                                          mu_l, rs_l, mu_h, rs_h,
                                                          g, bt, wpb, shift);
    }
  }
  mlp_k<<<512, 256, 0, stream>>>(low1b, high1b, (float*)d_out, w1b, mb1, w2b, mb2);
}

// Round 13
// 306.589 us; speedup vs baseline: 1.5326x; 1.0380x over previous
//
#include <hip/hip_runtime.h>
#include <math.h>

#define CHN 96
#define HW 16384
#define NWIN 31
#define SCALE_F 0.20412414523193154f
#define SCALE_L2 0.294488893f   // SCALE_F * log2(e): exp(s*SCALE) == exp2(s*SCALE_L2)

typedef __attribute__((ext_vector_type(8))) __bf16 bf16x8;
typedef __attribute__((ext_vector_type(4))) float f32x4;
typedef __attribute__((ext_vector_type(8))) unsigned short u16x8;

__device__ __forceinline__ int rfl(int v) { return __builtin_amdgcn_readfirstlane(v); }

__device__ __forceinline__ unsigned short f2bf(float f) {
  union { float f; unsigned u; } v; v.f = f;
  unsigned r = v.u + 0x7fffu + ((v.u >> 16) & 1u);
  return (unsigned short)(r >> 16);
}
__device__ __forceinline__ float bf2f(unsigned short h) {
  union { unsigned u; float f; } v; v.u = ((unsigned)h) << 16;
  return v.f;
}
__device__ __forceinline__ float fexp2(float x) {
#if __has_builtin(__builtin_amdgcn_exp2f)
  return __builtin_amdgcn_exp2f(x);
#else
  return __expf(x * 0.6931471806f);
#endif
}
__device__ __forceinline__ float ldv(const float* p, size_t i) { return p[i]; }
__device__ __forceinline__ float ldv(const unsigned short* p, size_t i) { return bf2f(p[i]); }
__device__ __forceinline__ bf16x8 ld8(const unsigned short* p) {
  return *(const bf16x8*)__builtin_assume_aligned(p, 16);
}
__device__ __forceinline__ u16x8 ld8u(const unsigned short* p) {
  return *(const u16x8*)__builtin_assume_aligned(p, 16);
}
__device__ __forceinline__ bf16x8 zf8() {
  union { unsigned long long u[2]; bf16x8 v; } z;
  z.u[0] = 0ull; z.u[1] = 0ull;
  return z.v;
}
__device__ __forceinline__ bf16x8 onesf8() {
  union { unsigned short s[8]; bf16x8 v; } o;
#pragma unroll
  for (int i = 0; i < 8; ++i) o.s[i] = 0x3F80;  // bf16 1.0
  return o.v;
}
// vector load helpers: 8 / 4 floats from fp32 or bf16 source
__device__ __forceinline__ void ld8f(const float* p, float* o) {
  float4 a = *(const float4*)__builtin_assume_aligned(p, 16);
  float4 b = *(const float4*)__builtin_assume_aligned(p + 4, 16);
  o[0] = a.x; o[1] = a.y; o[2] = a.z; o[3] = a.w;
  o[4] = b.x; o[5] = b.y; o[6] = b.z; o[7] = b.w;
}
__device__ __forceinline__ void ld8f(const unsigned short* p, float* o) {
  u16x8 v = ld8u(p);
#pragma unroll
  for (int u = 0; u < 8; ++u) o[u] = bf2f(v[u]);
}
__device__ __forceinline__ void ld4f(const float* p, float* o) {
  float4 a = *(const float4*)__builtin_assume_aligned(p, 16);
  o[0] = a.x; o[1] = a.y; o[2] = a.z; o[3] = a.w;
}
__device__ __forceinline__ void ld4f(const unsigned short* p, float* o) {
  ushort4 v = *(const ushort4*)__builtin_assume_aligned(p, 8);
  o[0] = bf2f(v.x); o[1] = bf2f(v.y); o[2] = bf2f(v.z); o[3] = bf2f(v.w);
}

// GELU via x*sigmoid(1.702x); |err vs exact| <= ~0.02 (within absmax budget)
__device__ __forceinline__ float gelu_sig(float x) {
  return x * __builtin_amdgcn_rcpf(1.f + __expf(-1.702f * x));
}

// ---------------- LN stats (pass 0 only), 1 px/thread, grid 256 ----------------
template <typename T>
__global__ __launch_bounds__(256) void ln2_k(const T* __restrict__ xl, const T* __restrict__ xh,
                                             float* __restrict__ mu_l, float* __restrict__ rs_l,
                                             float* __restrict__ mu_h, float* __restrict__ rs_h) {
  int which = blockIdx.x >> 7;           // 128 blocks per tensor
  int idx = (blockIdx.x & 127) * 256 + threadIdx.x;   // 0..32767 (2 batches x 16384 px)
  const T* xt = which ? xh : xl;
  float* mu = which ? mu_h : mu_l;
  float* rstd = which ? rs_h : rs_l;
  int b = idx >> 14, p = idx & 16383;
  const T* xp = xt + (size_t)b * CHN * HW + p;
  float s = 0.f, s2 = 0.f;
#pragma unroll 8
  for (int c = 0; c < CHN; ++c) {
    float v = ldv(xp, (size_t)c * HW);
    s += v;
    s2 = fmaf(v, v, s2);
  }
  float m = s * (1.f / 96.f);
  mu[idx] = m;
  rstd[idx] = rsqrtf(fmaf(-m, m, s2 * (1.f / 96.f)) + 1e-5f);
}

// ---------------- SE pool: partial sums, grid 768 = 2 b x 96 c x 4 px-chunks ----------------
template <typename T>
__global__ __launch_bounds__(256) void pool_k(const T* __restrict__ x,
                                              const float* __restrict__ mu,
                                              const float* __restrict__ rstd,
                                              float* __restrict__ poolp) {
  int blk = blockIdx.x;
  int chunk = blk & 3, bc = blk >> 2;    // bc in 0..191
  int b = bc / CHN, c = bc - b * CHN;
  const T* xp = x + (size_t)(b * CHN + c) * HW;
  const float* mup = mu + b * HW;
  const float* rp = rstd + b * HW;
  int t = threadIdx.x;
  float s = 0.f;
  int base = chunk * 4096;
#pragma unroll
  for (int it = 0; it < 4; ++it) {
    int p0 = base + it * 1024 + t * 4;
    float v4[4];
    ld4f(xp + p0, v4);
    float4 m4 = *(const float4*)&mup[p0];
    float4 r4 = *(const float4*)&rp[p0];
    s += (v4[0] - m4.x) * r4.x + (v4[1] - m4.y) * r4.y +
         (v4[2] - m4.z) * r4.z + (v4[3] - m4.w) * r4.w;
  }
  __shared__ float red[256];
  red[t] = s;
  __syncthreads();
  for (int k = 128; k > 0; k >>= 1) {
    if (t < k) red[t] += red[t + k];
    __syncthreads();
  }
  if (t == 0) poolp[chunk * 192 + bc] = red[0];
}

// ---------------- SE gate (sums 4 pool partials, applies g/bt) ----------------
__global__ __launch_bounds__(256) void se_k(const float* __restrict__ poolp,
                                            const float* __restrict__ g,
                                            const float* __restrict__ bt,
                                            const float* __restrict__ w1,
                                            const float* __restrict__ w2,
                                            float* __restrict__ s_se) {
  __shared__ float pl[192];
  int t = threadIdx.x;
  if (t < 192) {
    int c = t % CHN;
    float raw = poolp[t] + poolp[192 + t] + poolp[384 + t] + poolp[576 + t];
    pl[t] = g[c] * (raw * (1.f / 16384.f)) + bt[c];
  }
  __syncthreads();
  if (t >= 2 * CHN) return;
  int b = t / CHN, c = t % CHN;
  int i = c >> 5, cl = c & 31;
  const float* pg = &pl[b * CHN + i * 32];
  const float* w1p = w1 + i * 64;
  float z0 = 0.f, z1 = 0.f;
#pragma unroll 8
  for (int k = 0; k < 32; ++k) {
    float p = pg[k];
    z0 = fmaf(p, w1p[k], z0);
    z1 = fmaf(p, w1p[32 + k], z1);
  }
  z0 = fmaxf(z0, 0.f);
  z1 = fmaxf(z1, 0.f);
  float a = z0 * w2[i * 64 + cl * 2] + z1 * w2[i * 64 + cl * 2 + 1];
  s_se[t] = 1.f / (1.f + __expf(-a));
}

// ---------------- weight convert fp32 -> bf16 ----------------
__global__ __launch_bounds__(256) void cvt_k(const float* __restrict__ w1,
                                             const float* __restrict__ w2,
                                             const float* __restrict__ p0,
                                             const float* __restrict__ p1,
                                             const float* __restrict__ p2,
                                             const float* __restrict__ p3,
                                             const float* __restrict__ p4,
                                             const float* __restrict__ p5,
                                             const float* __restrict__ q0,
                                             const float* __restrict__ q1,
                                             unsigned short* __restrict__ w1b,
                                             unsigned short* __restrict__ w2b,
                                             unsigned short* __restrict__ wqb,
                                             unsigned short* __restrict__ wpb) {
  int i = blockIdx.x * 256 + threadIdx.x;
  if (i < 36864) {
    w1b[i] = f2bf(w1[i]);
    w2b[i] = f2bf(w2[i]);
  }
  if (i < 55296) {
    int tt = i / 9216, rem = i - tt * 9216;
    const float* ps[6] = {p0, p1, p2, p3, p4, p5};
    wqb[i] = f2bf(ps[tt][rem]);
  }
  if (i < 18432) {
    wpb[i] = f2bf(i < 9216 ? q0[i] : q1[i - 9216]);
  }
}

// ---------------- MFMA full-image QKV projection ----------------
// qkv slots [t][b]; Q/K (t=0,1,3,4) pixel-major [pix][96]; V (t=2,5) channel-major [c][HW].
template <typename T>
__global__ __launch_bounds__(256, 3) void proj_k(
    const T* __restrict__ lowp, const T* __restrict__ highp,
    const float* __restrict__ mu_l, const float* __restrict__ rs_l,
    const float* __restrict__ mu_h, const float* __restrict__ rs_h,
    const float* __restrict__ g, const float* __restrict__ bt,
    const float* __restrict__ s_se,
    const unsigned short* __restrict__ wqb,
    unsigned short* __restrict__ qkv) {
  __shared__ __align__(16) unsigned short sh[13312];  // Xl[64*104] | Xh[64*104]; later tb[4][32*104]
  unsigned short* Xl = sh;
  unsigned short* Xh = sh + 6656;
  int t = threadIdx.x;
  int lane = t & 63;
  int w = rfl(t >> 6);
  int n16 = lane & 15, quad = lane >> 4;
  int tile = blockIdx.x;
  int Pb = tile * 64;
  int b = Pb >> 14, rr0 = Pb & 16383;

  // ---- stage: thread's fixed 8 pixels = rr0 + (t&7)*8 .. +7 ----
  {
    int pg = t & 7;
    float mul8[8], rsl8[8], muh8[8], rsh8[8];
    ld8f(mu_l + (size_t)b * HW + rr0 + pg * 8, mul8);
    ld8f(rs_l + (size_t)b * HW + rr0 + pg * 8, rsl8);
    ld8f(mu_h + (size_t)b * HW + rr0 + pg * 8, muh8);
    ld8f(rs_h + (size_t)b * HW + rr0 + pg * 8, rsh8);
#pragma unroll
    for (int k = 0; k < 3; ++k) {
      int c = (t + k * 256) >> 3;
      float gc = g[c], bc = bt[c], sc = s_se[b * CHN + c];
      float xl8[8], xh8[8];
      ld8f(lowp + (size_t)(b * CHN + c) * HW + rr0 + pg * 8, xl8);
      ld8f(highp + (size_t)(b * CHN + c) * HW + rr0 + pg * 8, xh8);
      int cr = c + pg * 8; if (cr >= 96) cr -= 96;   // rotated col (row>>3 == pg)
#pragma unroll
      for (int u = 0; u < 8; ++u) {
        int px = pg * 8 + u;
        Xl[px * 104 + cr] = f2bf((xl8[u] - mul8[u]) * rsl8[u] * gc + bc);
        Xh[px * 104 + cr] = f2bf(((xh8[u] - muh8[u]) * rsh8[u] * gc + bc) * sc);
      }
    }
  }
  __syncthreads();

  // register-cache A-frags for BOTH the main (pixel-major) tensor and the V tensor
  int tmain = (0x4310 >> (4 * w)) & 15;          // w: 0->t0, 1->t1, 2->t3, 3->t4
  const unsigned short* Xm = (w == 0 || w == 3) ? Xl : Xh;
  const unsigned short* Xv = (w < 2) ? Xh : Xl;
  bf16x8 af[12], av[12];
  int rotb = n16 >> 3;
#pragma unroll
  for (int mi = 0; mi < 4; ++mi)
#pragma unroll
    for (int k = 0; k < 3; ++k) {
      int gidx = k * 4 + quad + 2 * mi + rotb; if (gidx >= 12) gidx -= 12;
      af[mi * 3 + k] = ld8(&Xm[(mi * 16 + n16) * 104 + gidx * 8]);
      av[mi * 3 + k] = ld8(&Xv[(mi * 16 + n16) * 104 + gidx * 8]);
    }
  __syncthreads();   // X dead; tb overlays

  unsigned short* tw = sh + w * 3328;
#pragma unroll
  for (int half = 0; half < 2; ++half) {
#pragma unroll
    for (int ni = 0; ni < 6; ++ni) {
      f32x4 a0 = {0.f, 0.f, 0.f, 0.f}, a1 = {0.f, 0.f, 0.f, 0.f};
#pragma unroll
      for (int k = 0; k < 3; ++k) {
        bf16x8 bf = ld8(&wqb[((size_t)tmain * 96 + ni * 16 + n16) * 96 + k * 32 + quad * 8]);
        a0 = __builtin_amdgcn_mfma_f32_16x16x32_bf16(af[(half * 2 + 0) * 3 + k], bf, a0, 0, 0, 0);
        a1 = __builtin_amdgcn_mfma_f32_16x16x32_bf16(af[(half * 2 + 1) * 3 + k], bf, a1, 0, 0, 0);
      }
#pragma unroll
      for (int r = 0; r < 4; ++r) {
        tw[(quad * 4 + r) * 104 + ni * 16 + n16] = f2bf(a0[r]);
        tw[(16 + quad * 4 + r) * 104 + ni * 16 + n16] = f2bf(a1[r]);
      }
    }
    // wave-local readout (per-wave DS ops in-order; no barrier)
#pragma unroll
    for (int c6 = 0; c6 < 6; ++c6) {
      int chunk = lane + 64 * c6;
      int pl2 = chunk / 12, kb2 = chunk - pl2 * 12;
      u16x8 v = ld8u(&tw[pl2 * 104 + kb2 * 8]);
      size_t pix = (size_t)rr0 + half * 32 + pl2;
      *(u16x8*)&qkv[((size_t)(tmain * 2 + b) * HW + pix) * 96 + kb2 * 8] = v;
    }
  }

  // V units from register-cached av
  int tv = (w < 2) ? 2 : 5;
  int nbase = (w & 1) * 3;
#pragma unroll
  for (int jj = 0; jj < 3; ++jj) {
    int ni = nbase + jj;
    f32x4 acc[4];
#pragma unroll
    for (int mi = 0; mi < 4; ++mi) { f32x4 z = {0.f, 0.f, 0.f, 0.f}; acc[mi] = z; }
#pragma unroll
    for (int k = 0; k < 3; ++k) {
      bf16x8 bf = ld8(&wqb[((size_t)tv * 96 + ni * 16 + n16) * 96 + k * 32 + quad * 8]);
#pragma unroll
      for (int mi = 0; mi < 4; ++mi)
        acc[mi] = __builtin_amdgcn_mfma_f32_16x16x32_bf16(av[mi * 3 + k], bf, acc[mi], 0, 0, 0);
    }
    int feat = ni * 16 + n16;
    size_t rowbase = ((size_t)(tv * 2 + b) * CHN + feat) * HW + rr0;
#pragma unroll
    for (int mi = 0; mi < 4; ++mi) {
      ushort4 o4;
      o4.x = f2bf(acc[mi][0]);
      o4.y = f2bf(acc[mi][1]);
      o4.z = f2bf(acc[mi][2]);
      o4.w = f2bf(acc[mi][3]);
      *(ushort4*)&qkv[rowbase + mi * 16 + quad * 4] = o4;
    }
  }
}

// ---------------- MFMA window attention (both dirs fused; 8-wave ni-split) ----------------
// grid = 3844 blocks x 512 threads. wave w = (h = w&3, half = w>>2); each wave handles
// 2 of 4 ni Q-row groups -> per-wave MFMA chain 40->20, exp 64->32 (latency-bound fix).
// P32 is per-h; the two waves of one h touch DISJOINT rows (0-31 vs 32-63) so the
// wave-local DS-ordering argument still holds (no extra barrier). K-frags loaded by
// both halves (same block -> L2 hit, no HBM delta).
// XCD swizzle: 3844 % 8 = 4 -> bijective chunked variant (q=480, r=4).
// [R7 ERRATA: naive remap skipped half the windows; absmax was the tell.]
// [R9 ERRATA: V must be staged cooperatively through LDS; coalescing is cross-lane.]
__global__ __launch_bounds__(512, 6) void attn_k(
    const unsigned short* __restrict__ qkv,
    unsigned short* __restrict__ Owin, int shift) {
  __shared__ __align__(16) unsigned short shb[16128];  // Vs[96*72]=6912 | P32[4*64*36]=9216
  unsigned short* Vs = shb;                            // later overlaid by Os[64*104]
  unsigned short* P32 = shb + 6912;
  unsigned short* Os = shb;

  int bid0 = blockIdx.x;
  int x8 = bid0 & 7, y8 = bid0 >> 3;
  int bid = (x8 < 4 ? x8 * 481 : 1924 + (x8 - 4) * 480) + y8;  // bijective on [0,3844)
  int dir = bid / 1922;
  int rem = bid - dir * 1922;
  int b = rem / 961;
  int win = rem - b * 961;
  int wy = win / NWIN, wx = win % NWIN;
  int t = threadIdx.x;
  int lane = t & 63;
  int w = rfl(t >> 6);          // 0..7
  int h = w & 3, half = w >> 2; // head, ni-half
  int nib = half * 2;           // ni base: 0 or 2
  int n16 = lane & 15, quad = lane >> 4;

  // ---- T14: issue ALL global loads (V x3, Q x2, K x4) before any LDS write ----
  ushort4 vv[3];
  int vdst[3];
  {
    const unsigned short* vbase = qkv + (size_t)((dir * 3 + 2) * 2 + b) * CHN * HW;
#pragma unroll
    for (int k = 0; k < 3; ++k) {
      int i = t + k * 512;
      int c = i >> 4, ry = (i >> 1) & 7, hx = i & 1;
      int gy = (wy * 4 + ry + shift) & 127;
      int gx = (wx * 4 + hx * 4 + shift) & 127;
      vv[k] = *(const ushort4*)(vbase + (size_t)c * HW + gy * 128 + gx);
      vdst[k] = c * 72 + ry * 8 + hx * 4;
    }
  }

  bf16x8 qa[2], kb4[4];
  {
    const unsigned short* qpm = qkv + (size_t)((dir * 3 + 0) * 2 + b) * CHN * HW;
    const unsigned short* kpm = qkv + (size_t)((dir * 3 + 1) * 2 + b) * CHN * HW;
    if (quad < 3) {
#pragma unroll
      for (int ni = 0; ni < 2; ++ni) {
        int n = (nib + ni) * 16 + n16;
        int gy = (wy * 4 + (n >> 3) + shift) & 127;
        int gx = (wx * 4 + (n & 7) + shift) & 127;
        size_t pix = (size_t)gy * 128 + gx;
        qa[ni] = ld8(&qpm[pix * 96 + h * 24 + quad * 8]);
      }
#pragma unroll
      for (int mi = 0; mi < 4; ++mi) {
        int n = mi * 16 + n16;
        int gy = (wy * 4 + (n >> 3) + shift) & 127;
        int gx = (wx * 4 + (n & 7) + shift) & 127;
        size_t pix = (size_t)gy * 128 + gx;
        kb4[mi] = ld8(&kpm[pix * 96 + h * 24 + quad * 8]);
      }
    } else {
#pragma unroll
      for (int ni = 0; ni < 2; ++ni) qa[ni] = zf8();
#pragma unroll
      for (int mi = 0; mi < 4; ++mi) kb4[mi] = zf8();
    }
  }

  // commit V to LDS (loads above already in flight)
#pragma unroll
  for (int k = 0; k < 3; ++k) *(ushort4*)&Vs[vdst[k]] = vv[k];
  __syncthreads();

  const int hP = h * (64 * 36);

  f32x4 sa[2][4];
#pragma unroll
  for (int ni = 0; ni < 2; ++ni)
#pragma unroll
    for (int mi = 0; mi < 4; ++mi) {
      f32x4 z = {0.f, 0.f, 0.f, 0.f};
      sa[ni][mi] = __builtin_amdgcn_mfma_f32_16x16x32_bf16(qa[ni], kb4[mi], z, 0, 0, 0);
    }

  // unnormalized exponentials (no-max softmax; scores bounded)
#pragma unroll
  for (int ni = 0; ni < 2; ++ni)
#pragma unroll
    for (int mi = 0; mi < 4; ++mi)
#pragma unroll
      for (int r = 0; r < 4; ++r)
        sa[ni][mi][r] = fexp2(sa[ni][mi][r] * SCALE_L2);

  const bf16x8 ones = onesf8();
  f32x4 oa[2][2];
  f32x4 sacc[2];
#pragma unroll
  for (int ni = 0; ni < 2; ++ni) {
    f32x4 z = {0.f, 0.f, 0.f, 0.f};
    oa[ni][0] = z; oa[ni][1] = z; sacc[ni] = z;
  }
#pragma unroll
  for (int s = 0; s < 2; ++s) {
    // P32 rows (nib+ni)*16+...: halves write disjoint row ranges of the per-h region;
    // write->read is same-wave (in-order DS), no barrier needed
#pragma unroll
    for (int ni = 0; ni < 2; ++ni)
#pragma unroll
      for (int r = 0; r < 4; ++r) {
#pragma unroll
        for (int mm = 0; mm < 2; ++mm) {
          int mi = s * 2 + mm;
          P32[hP + ((nib + ni) * 16 + quad * 4 + r) * 36 + mm * 16 + n16] = f2bf(sa[ni][mi][r]);
        }
      }
    bf16x8 pa[2];
#pragma unroll
    for (int ni = 0; ni < 2; ++ni)
      pa[ni] = ld8(&P32[hP + ((nib + ni) * 16 + n16) * 36 + quad * 8]);
    bf16x8 vb0 = ld8(&Vs[(h * 24 + n16) * 72 + s * 32 + quad * 8]);
    bf16x8 vb1 = (n16 < 8) ? ld8(&Vs[(h * 24 + 16 + n16) * 72 + s * 32 + quad * 8]) : zf8();
#pragma unroll
    for (int ni = 0; ni < 2; ++ni) {
      oa[ni][0] = __builtin_amdgcn_mfma_f32_16x16x32_bf16(pa[ni], vb0, oa[ni][0], 0, 0, 0);
      oa[ni][1] = __builtin_amdgcn_mfma_f32_16x16x32_bf16(pa[ni], vb1, oa[ni][1], 0, 0, 0);
      sacc[ni] = __builtin_amdgcn_mfma_f32_16x16x32_bf16(pa[ni], ones, sacc[ni], 0, 0, 0);
    }
  }

  // normalize O by MFMA-computed row sums (same accumulator layout: row = quad*4+r)
#pragma unroll
  for (int ni = 0; ni < 2; ++ni)
#pragma unroll
    for (int r = 0; r < 4; ++r) {
      float inv = __builtin_amdgcn_rcpf(sacc[ni][r]);
      oa[ni][0][r] *= inv;
      oa[ni][1][r] *= inv;
    }
  __syncthreads();   // Vs+P32 dead; Os overlays

  // stage O -> Os[px][96] (pad 104), then coalesced 16B stores
#pragma unroll
  for (int ni = 0; ni < 2; ++ni)
#pragma unroll
    for (int r = 0; r < 4; ++r) {
      int n = (nib + ni) * 16 + quad * 4 + r;
      Os[n * 104 + h * 24 + n16] = f2bf(oa[ni][0][r]);
      if (n16 < 8) Os[n * 104 + h * 24 + 16 + n16] = f2bf(oa[ni][1][r]);
    }
  __syncthreads();

  {
    unsigned short* obase = Owin + (size_t)((dir * 2 + b) * 961 + win) * 64 * CHN;
#pragma unroll
    for (int k = 0; k < 2; ++k) {
      int i = t + k * 512;               // 0..1023, need 0..767
      if (i < 768) {
        int px = i / 12, cb = i - px * 12;
        u16x8 v = ld8u(&Os[px * 104 + cb * 8]);
        *(u16x8*)&obase[px * CHN + cb * 8] = v;
      }
    }
  }
}

// ---------------- MFMA combine + fused next-pass LN stats (low+high fused) ----------------
// grid 1024; XCD-chunk swizzle (1024 = 8*128, divisible -> simple form is bijective).
template <typename T>
__global__ __launch_bounds__(256) void combine_k(
    const T* __restrict__ base_l, const T* __restrict__ base_h,
    unsigned short* __restrict__ out_l, unsigned short* __restrict__ out_h,
    const unsigned short* __restrict__ Owin,
    float* __restrict__ mu_lp, float* __restrict__ rs_lp,
    float* __restrict__ mu_hp, float* __restrict__ rs_hp,
    const float* __restrict__ g, const float* __restrict__ bt,
    const unsigned short* __restrict__ wpb2, int shift) {
  __shared__ __align__(16) unsigned short sb[96 * 72];   // at [64][104] then ot [96][72]
  __shared__ float red[2][4][64];
  unsigned short* at = sb;
  unsigned short* ot = sb;
  int t = threadIdx.x;
  int lane = t & 63;
  int w = rfl(t >> 6);
  int n16 = lane & 15, quad = lane >> 4;
  int wg = (blockIdx.x & 7) * 128 + (blockIdx.x >> 3);   // bijective XCD-chunk swizzle
  int sel = wg >> 9;
  int tile = wg & 511;                   // 0..511
  const T* base = sel ? base_h : base_l;
  unsigned short* outp = sel ? out_h : out_l;
  float* mu = sel ? mu_hp : mu_lp;
  float* rstd = sel ? rs_hp : rs_lp;
  const unsigned short* wpb = wpb2 + sel * 9216;

#pragma unroll
  for (int k = 0; k < 3; ++k) {
    int i = t + k * 256;
    int px = i / 12, cb = i - px * 12;
    int Ps = tile * 64 + px;
    int b = Ps >> 14, rem = Ps & 16383;
    int ys = rem >> 7, xs = rem & 127;
    int wyh = ys >> 2, wxh = xs >> 2;
    float acc[8];
#pragma unroll
    for (int u = 0; u < 8; ++u) acc[u] = 0.f;
    for (int dy = 0; dy < 2; ++dy) {
      int wyc = wyh - 1 + dy;
      if ((unsigned)wyc > 30u) continue;
      int py = ys - wyc * 4;
      for (int dx = 0; dx < 2; ++dx) {
        int wxc = wxh - 1 + dx;
        if ((unsigned)wxc > 30u) continue;
        int pxl = xs - wxc * 4;
        size_t o = ((size_t)((sel * 2 + b) * 961 + wyc * 31 + wxc) * 64 + py * 8 + pxl) * CHN + cb * 8;
        u16x8 v = ld8u(&Owin[o]);
#pragma unroll
        for (int u = 0; u < 8; ++u) acc[u] += bf2f(v[u]);
      }
    }
    union { u16x8 v; unsigned short s[8]; } pk;
#pragma unroll
    for (int u = 0; u < 8; ++u) pk.s[u] = f2bf(acc[u]);
    *(u16x8*)&at[px * 104 + cb * 8] = pk.v;
  }
  __syncthreads();

  bf16x8 af[3];
#pragma unroll
  for (int k = 0; k < 3; ++k)
    af[k] = ld8(&at[(w * 16 + n16) * 104 + k * 32 + quad * 8]);

  f32x4 acc6[6];
#pragma unroll
  for (int ni = 0; ni < 6; ++ni) {
    f32x4 z = {0.f, 0.f, 0.f, 0.f};
    acc6[ni] = z;
#pragma unroll
    for (int k = 0; k < 3; ++k) {
      bf16x8 bf = ld8(&wpb[(ni * 16 + n16) * 96 + k * 32 + quad * 8]);
      acc6[ni] = __builtin_amdgcn_mfma_f32_16x16x32_bf16(af[k], bf, acc6[ni], 0, 0, 0);
    }
  }
  __syncthreads();

#pragma unroll
  for (int ni = 0; ni < 6; ++ni)
#pragma unroll
    for (int r = 0; r < 4; ++r)
      ot[(ni * 16 + n16) * 72 + w * 16 + quad * 4 + r] = f2bf(acc6[ni][r]);
  __syncthreads();

  int Ps0 = tile * 64;
  int b = Ps0 >> 14, rem0 = Ps0 & 16383;
  int ys = rem0 >> 7, xs0 = rem0 & 127;
  int yt = (ys + shift) & 127;
  float icy = (ys >= 4 && ys <= 123) ? 0.5f : 1.f;
  int px = t & 63, c0w = t >> 6;
  int xs = xs0 + px;
  int xt = (xs + shift) & 127;
  float icx = (xs >= 4 && xs <= 123) ? 0.5f : 1.f;
  float invc = icy * icx;
  int pt = b * HW + yt * 128 + xt;
  float m = mu[pt], rs = rstd[pt];
  size_t pixoff = (size_t)yt * 128 + xt;
  float s = 0.f, sq = 0.f;
#pragma unroll
  for (int k = 0; k < 24; ++k) {
    int o = c0w + 4 * k;
    size_t gidx = ((size_t)b * CHN + o) * HW + pixoff;
    float bv = ldv(base, gidx);
    float lnv = (bv - m) * rs * g[o] + bt[o];
    float v = bv + lnv + bf2f(ot[o * 72 + px]) * invc;
    outp[gidx] = f2bf(v);
    s += v;
    sq = fmaf(v, v, sq);
  }
  red[0][c0w][px] = s;
  red[1][c0w][px] = sq;
  __syncthreads();
  if (t < 64) {
    int px2 = t;
    float ss = red[0][0][px2] + red[0][1][px2] + red[0][2][px2] + red[0][3][px2];
    float qq = red[1][0][px2] + red[1][1][px2] + red[1][2][px2] + red[1][3][px2];
    int xs2 = xs0 + px2;
    int xt2 = (xs2 + shift) & 127;
    int pt2 = b * HW + yt * 128 + xt2;
    float mm = ss * (1.f / 96.f);
    float var = fmaf(-mm, mm, qq * (1.f / 96.f));
    mu[pt2] = mm;
    rstd[pt2] = rsqrtf(var + 1e-5f);
  }
}

// ---------------- MFMA MLP ----------------
// 128-px tile, 4 waves, 512 blocks (2/CU). L2-load-latency bound: weight-frag
// reuse GEMM1 1:8, GEMM2 1:4; explicit prefetch arrays force deep MLP.
// NOTE: decode is built for a 512-block grid (sel = bid>>8, tile = bid&255).
__global__ __launch_bounds__(256, 2) void mlp_k(
    const unsigned short* __restrict__ x_l, const unsigned short* __restrict__ x_h,
    float* __restrict__ outp,
    const unsigned short* __restrict__ w1b, const float* __restrict__ b1,
    const unsigned short* __restrict__ w2b, const float* __restrict__ b2) {
  __shared__ __align__(16) unsigned char smem[51200];
  unsigned short* Xa = (unsigned short*)smem;   // [128][104] rotated groups
  unsigned short* Ha = (unsigned short*)smem;   // [128][200]
  float* Ot = (float*)smem;                     // [96][132]

  int t = threadIdx.x;
  int lane = t & 63;
  int w = rfl(t >> 6);
  int n16 = lane & 15, quad = lane >> 4;
  int sel = blockIdx.x >> 8;
  int tile = blockIdx.x & 255;
  const unsigned short* x = sel ? x_h : x_l;
  float* op = outp + (size_t)sel * (2 * CHN * HW);
  int Pb = tile * 128;
  int b = Pb >> 14, rr0 = Pb & 16383;

  // ---- stage: issue all 6 x-loads, then all 18 w1 frags + 6 biases (deep MLP),
  // then scatter x into Xa with group-rotation swizzle ----
  u16x8 xv6[6];
  int cc6[6], pp6[6];
#pragma unroll
  for (int k = 0; k < 6; ++k) {
    int i = t + k * 256;                 // 0..1535
    cc6[k] = i >> 4; pp6[k] = i & 15;    // 96 ch x 16 px-groups
    xv6[k] = ld8u(&x[((size_t)b * CHN + cc6[k]) * HW + rr0 + pp6[k] * 8]);
  }
  bf16x8 wf[18];
  float b1v6[6];
#pragma unroll
  for (int h2 = 0; h2 < 2; ++h2)
#pragma unroll
    for (int ni = 0; ni < 3; ++ni) {
      int nrow = h2 * 192 + w * 48 + ni * 16 + n16;
#pragma unroll
      for (int kk = 0; kk < 3; ++kk)
        wf[(h2 * 3 + ni) * 3 + kk] = ld8(&w1b[(size_t)nrow * 96 + kk * 32 + quad * 8]);
      b1v6[h2 * 3 + ni] = b1[nrow];
    }
#pragma unroll
  for (int k = 0; k < 6; ++k) {
    int cr = cc6[k] + 8 * pp6[k];
    if (cr >= 96) cr -= 96;
    if (cr >= 96) cr -= 96;
#pragma unroll
    for (int u = 0; u < 8; ++u) Xa[(pp6[k] * 8 + u) * 104 + cr] = xv6[k][u];
  }
  __syncthreads();

  bf16x8 af[24];
  int rotb = n16 >> 3;
#pragma unroll
  for (int mi = 0; mi < 8; ++mi)
#pragma unroll
    for (int k = 0; k < 3; ++k) {
      int gidx = k * 4 + quad + 2 * mi + rotb;
      if (gidx >= 24) gidx -= 24; else if (gidx >= 12) gidx -= 12;
      af[mi * 3 + k] = ld8(&Xa[(mi * 16 + n16) * 104 + gidx * 8]);
    }
  __syncthreads();   // Xa dead; Ha overlays

  int ph = w & 1, fh = w >> 1;
  f32x4 acc2[4][3];
#pragma unroll
  for (int g2 = 0; g2 < 4; ++g2)
#pragma unroll
    for (int ni = 0; ni < 3; ++ni) { f32x4 z = {0.f, 0.f, 0.f, 0.f}; acc2[g2][ni] = z; }

#pragma unroll
  for (int half = 0; half < 2; ++half) {
    // GEMM1: wave's 48 features x 128 px; weight frag reused over 8 mi (1:8)
#pragma unroll
    for (int ni = 0; ni < 3; ++ni) {
      f32x4 acc[8];
#pragma unroll
      for (int mi = 0; mi < 8; ++mi) { f32x4 z = {0.f, 0.f, 0.f, 0.f}; acc[mi] = z; }
#pragma unroll
      for (int kk = 0; kk < 3; ++kk) {
        bf16x8 bf = wf[(half * 3 + ni) * 3 + kk];
#pragma unroll
        for (int mi = 0; mi < 8; ++mi)
          acc[mi] = __builtin_amdgcn_mfma_f32_16x16x32_bf16(af[mi * 3 + kk], bf, acc[mi], 0, 0, 0);
      }
      int fl = w * 48 + ni * 16 + n16;
      float b1v = b1v6[half * 3 + ni];
#pragma unroll
      for (int mi = 0; mi < 8; ++mi)
#pragma unroll
        for (int r = 0; r < 4; ++r)
          Ha[(mi * 16 + quad * 4 + r) * 200 + fl] = f2bf(gelu_sig(acc[mi][r] + b1v));
    }
    __syncthreads();

    // GEMM2: wave = (ph px-half: 4 groups of 16 px, fh feat-half: 48 out-features);
    // w2 frags prefetched in batches of 9, each reused over 4 px-groups (1:4)
#pragma unroll
    for (int kc = 0; kc < 2; ++kc) {
      bf16x8 w2f[9];
#pragma unroll
      for (int kk = 0; kk < 3; ++kk)
#pragma unroll
        for (int ni = 0; ni < 3; ++ni)
          w2f[kk * 3 + ni] = ld8(&w2b[((size_t)(fh * 48 + ni * 16 + n16)) * 384 +
                                      half * 192 + (kc * 3 + kk) * 32 + quad * 8]);
#pragma unroll
      for (int kk = 0; kk < 3; ++kk) {
        int k0 = kc * 3 + kk;
        bf16x8 a2[4];
#pragma unroll
        for (int g2 = 0; g2 < 4; ++g2)
          a2[g2] = ld8(&Ha[((ph * 4 + g2) * 16 + n16) * 200 + k0 * 32 + quad * 8]);
#pragma unroll
        for (int ni = 0; ni < 3; ++ni)
#pragma unroll
          for (int g2 = 0; g2 < 4; ++g2)
            acc2[g2][ni] = __builtin_amdgcn_mfma_f32_16x16x32_bf16(a2[g2], w2f[kk * 3 + ni], acc2[g2][ni], 0, 0, 0);
      }
    }
    __syncthreads();   // Ha(half) consumed; safe for next half's GEMM1 writes / Ot overlay
  }

  // Ot overlay (Ha dead)
#pragma unroll
  for (int g2 = 0; g2 < 4; ++g2)
#pragma unroll
    for (int ni = 0; ni < 3; ++ni)
#pragma unroll
      for (int r = 0; r < 4; ++r)
        Ot[(fh * 48 + ni * 16 + n16) * 132 + (ph * 4 + g2) * 16 + quad * 4 + r] = acc2[g2][ni][r];
  __syncthreads();

#pragma unroll
  for (int k = 0; k < 12; ++k) {
    int i = t + k * 256;
    int o = i >> 5, pg = i & 31;
    size_t gbase = ((size_t)b * CHN + o) * HW + rr0 + pg * 4;
    ushort4 xv = *(const ushort4*)&x[gbase];
    float4 ov = *(const float4*)&Ot[o * 132 + pg * 4];
    float bb = b2[o];
    float4 res;
    res.x = bf2f(xv.x) + ov.x + bb;
    res.y = bf2f(xv.y) + ov.y + bb;
    res.z = bf2f(xv.z) + ov.z + bb;
    res.w = bf2f(xv.w) + ov.w + bb;
    *(float4*)&op[gbase] = res;
  }
}

extern "C" void kernel_launch(void* const* d_in, const int* in_sizes, int n_in,
                              void* d_out, int out_size, void* d_ws, size_t ws_size,
                              hipStream_t stream) {
  (void)in_sizes; (void)n_in; (void)out_size; (void)ws_size;
  const float* low   = (const float*)d_in[0];
  const float* high  = (const float*)d_in[1];
  const float* ln1_g = (const float*)d_in[2];
  const float* ln1_b = (const float*)d_in[3];
  const float* ln2_g = (const float*)d_in[4];
  const float* ln2_b = (const float*)d_in[5];
  const float* se_w1 = (const float*)d_in[6];
  const float* se_w2 = (const float*)d_in[7];
  const float* wq_l  = (const float*)d_in[8];
  const float* wk_h  = (const float*)d_in[9];
  const float* wv_h  = (const float*)d_in[10];
  const float* wq_h  = (const float*)d_in[11];
  const float* wk_l  = (const float*)d_in[12];
  const float* wv_l  = (const float*)d_in[13];
  const float* wp_l  = (const float*)d_in[14];
  const float* wp_h  = (const float*)d_in[15];
  const float* mw1   = (const float*)d_in[16];
  const float* mb1   = (const float*)d_in[17];
  const float* mw2   = (const float*)d_in[18];
  const float* mb2   = (const float*)d_in[19];

  // ws layout, ~98.4 MB total (poison-fill WRITE_SIZE shows ws = 256 MiB)
  float* ws = (float*)d_ws;
  unsigned short* w1b = (unsigned short*)ws;
  unsigned short* w2b = w1b + 36864;
  unsigned short* wqb = w2b + 36864;
  unsigned short* wpb = wqb + 55296;                  // front total 147456 shorts = 73728 floats
  float* mu_l  = ws + 73728;
  float* rs_l  = mu_l + 32768;
  float* mu_h  = rs_l + 32768;
  float* rs_h  = mu_h + 32768;
  float* poolb = rs_h + 32768;                        // 768 partials (4 chunks x 192)
  float* s_se  = poolb + 768;
  unsigned short* low1b  = (unsigned short*)(s_se + 256);
  unsigned short* high1b = low1b + 3145728;
  unsigned short* qkv    = high1b + 3145728;          // 18874368 shorts
  unsigned short* Owin   = qkv + 18874368;            // 23617536 shorts (2 dirs x 2 b)

  cvt_k<<<216, 256, 0, stream>>>(mw1, mw2, wq_l, wk_h, wv_h, wq_h, wk_l, wv_l,
                                 wp_l, wp_h, w1b, w2b, wqb, wpb);

  ln2_k<float><<<256, 256, 0, stream>>>(low, high, mu_l, rs_l, mu_h, rs_h);

  for (int pass = 0; pass < 2; ++pass) {
    const float* g  = pass ? ln2_g : ln1_g;
    const float* bt = pass ? ln2_b : ln1_b;
    int shift = pass ? 4 : 0;

    if (pass == 0) {
      pool_k<float><<<768, 256, 0, stream>>>(high, mu_h, rs_h, poolb);
      se_k<<<1, 256, 0, stream>>>(poolb, g, bt, se_w1, se_w2, s_se);
      proj_k<float><<<512, 256, 0, stream>>>(low, high, mu_l, rs_l, mu_h, rs_h,
                                             g, bt, s_se, wqb, qkv);
      attn_k<<<2 * 1922, 512, 0, stream>>>(qkv, Owin, shift);
      combine_k<float><<<1024, 256, 0, stream>>>(low, high, low1b, high1b, Owin,
                                                 mu_l, rs_l, mu_h, rs_h,
                                                 g, bt, wpb, shift);
    } else {
      pool_k<unsigned short><<<768, 256, 0, stream>>>(high1b, mu_h, rs_h, poolb);
      se_k<<<1, 256, 0, stream>>>(poolb, g, bt, se_w1, se_w2, s_se);
      proj_k<unsigned short><<<512, 256, 0, stream>>>(low1b, high1b, mu_l, rs_l, mu_h, rs_h,
                                                      g, bt, s_se, wqb, qkv);
      attn_k<<<2 * 1922, 512, 0, stream>>>(qkv, Owin, shift);
      combine_k<unsigned short><<<1024, 256, 0, stream>>>(low1b, high1b, low1b, high1b, Owin,
                                                          mu_l, rs_l, mu_h, rs_h,
                                                          g, bt, wpb, shift);
    }
  }
  mlp_k<<<512, 256, 0, stream>>>(low1b, high1b, (float*)d_out, w1b, mb1, w2b, mb2);
}